// Round 11
// baseline (549.951 us; speedup 1.0000x reference)
//
#include <hip/hip_runtime.h>
#include <math.h>

#define F_IN 512
#define NCLS 40
#define BSH 7                 // 128 nodes per bucket
#define BNODES (1 << BSH)
#define CH 16384              // edges per partition block

typedef __attribute__((ext_vector_type(8))) short bf16x8;
typedef __attribute__((ext_vector_type(4))) float f32x4;

__device__ __forceinline__ f32x4 mfma_bf16(bf16x8 a, bf16x8 b, f32x4 c){
  return __builtin_amdgcn_mfma_f32_16x16x32_bf16(a, b, c, 0, 0, 0);
}
__device__ __forceinline__ float fsigm(float x){ return 1.f/(1.f+__expf(-x)); }
__device__ __forceinline__ float ftanh(float x){ return 1.f - 2.f/(__expf(2.f*x)+1.f); }
__device__ __forceinline__ unsigned short f2bf(float f){
  unsigned u = __float_as_uint(f);
  return (unsigned short)((u + 0x7fffu + ((u>>16)&1u)) >> 16);
}
__device__ __forceinline__ float bf2f(unsigned short h){
  return __uint_as_float(((unsigned)h) << 16);
}
// packed f32x2 -> bf16x2 (RTNE, HW instruction)
__device__ __forceinline__ unsigned cvtpk(float lo, float hi){
  unsigned r;
  asm("v_cvt_pk_bf16_f32 %0, %1, %2" : "=v"(r) : "v"(lo), "v"(hi));
  return r;
}

// ================= CSR build: block-aggregated partition (no global atomics) ========
__global__ __launch_bounds__(256) void k_pcount(const int* __restrict__ ei, int e, int n,
                                                int nb, int* __restrict__ bhist){
  __shared__ int h[1024];
  int b = blockIdx.x, t = threadIdx.x;
  for (int i = t; i < nb; i += 256) h[i] = 0;
  __syncthreads();
  int tot = e + n;
  int base = b*CH;
  int lim = min(base + CH, tot);
  for (int i = base + t; i < lim; i += 256){
    int d = (i < e) ? ei[e + i] : (i - e);
    atomicAdd(&h[d >> BSH], 1);
  }
  __syncthreads();
  for (int i = t; i < nb; i += 256) bhist[(size_t)b*nb + i] = h[i];
}

__global__ __launch_bounds__(256) void k_pscan1(int* __restrict__ bhist, int nb, int B,
                                                int* __restrict__ bcnt){
  int i = blockIdx.x*256 + threadIdx.x;
  if (i >= nb) return;
  int run = 0;
  for (int b = 0; b < B; b++){
    int v = bhist[(size_t)b*nb + i];
    bhist[(size_t)b*nb + i] = run;
    run += v;
  }
  bcnt[i] = run;
}

__global__ __launch_bounds__(256) void k_pscan2(const int* __restrict__ bcnt, int nb, int tot,
                                                int* __restrict__ bbase,
                                                int* __restrict__ rowptr, int n){
  __shared__ int sb[256];
  __shared__ int carry;
  int t = threadIdx.x;
  if (t == 0) carry = 0;
  __syncthreads();
  for (int c0 = 0; c0 < nb; c0 += 256){
    int v = (c0 + t < nb) ? bcnt[c0 + t] : 0;
    sb[t] = v; __syncthreads();
    for (int off = 1; off < 256; off <<= 1){
      int u = (t >= off) ? sb[t-off] : 0; __syncthreads();
      sb[t] += u; __syncthreads();
    }
    if (c0 + t < nb) bbase[c0 + t] = carry + sb[t] - v;
    __syncthreads();
    if (t == 0) carry += sb[255];
    __syncthreads();
  }
  if (t == 0){ bbase[nb] = carry; rowptr[n] = tot; }
}

__global__ __launch_bounds__(256) void k_pscatter(const int* __restrict__ ei, int e, int n,
                                                  int nb, const int* __restrict__ bhist,
                                                  const int* __restrict__ bbase,
                                                  unsigned* __restrict__ bedges){
  __shared__ int cur[1024];
  int b = blockIdx.x, t = threadIdx.x;
  for (int i = t; i < nb; i += 256)
    cur[i] = bbase[i] + bhist[(size_t)b*nb + i];
  __syncthreads();
  int tot = e + n;
  int base = b*CH;
  int lim = min(base + CH, tot);
  for (int i = base + t; i < lim; i += 256){
    int s, d;
    if (i < e){ s = ei[i]; d = ei[e + i]; } else { s = i - e; d = s; }
    int pos = atomicAdd(&cur[d >> BSH], 1);
    bedges[pos] = (unsigned)s | ((unsigned)(d & (BNODES-1)) << 20);
  }
}

__global__ __launch_bounds__(256) void k_bbuild(const unsigned* __restrict__ bedges,
                                                const int* __restrict__ bbase,
                                                int* __restrict__ rowptr, int* __restrict__ col, int n){
  int b = blockIdx.x;
  int t = threadIdx.x;
  __shared__ int hist[BNODES];
  __shared__ int sc[BNODES];
  __shared__ int cur[BNODES];
  int beg = bbase[b], end = bbase[b+1];
  if (t < BNODES) hist[t] = 0;
  __syncthreads();
  for (int i = beg + t; i < end; i += 256)
    atomicAdd(&hist[bedges[i] >> 20], 1);
  __syncthreads();
  int v = (t < BNODES) ? hist[t] : 0;
  if (t < BNODES) sc[t] = v;
  __syncthreads();
  for (int off = 1; off < BNODES; off <<= 1){
    int u = (t >= off && t < BNODES) ? sc[t-off] : 0;
    __syncthreads();
    if (t < BNODES) sc[t] += u;
    __syncthreads();
  }
  if (t < BNODES){
    int excl = sc[t] - v;
    int node = (b << BSH) + t;
    if (node < n) rowptr[node] = beg + excl;
    cur[t] = excl;
  }
  __syncthreads();
  for (int i = beg + t; i < end; i += 256){
    unsigned pk = bedges[i];
    int pos = atomicAdd(&cur[pk >> 20], 1);
    col[beg + pos] = (int)(pk & 0xFFFFFu);
  }
}

// ================= fused weight prep (all conversions, 1 dispatch) =================
__global__ __launch_bounds__(256) void k_prep(
    const float* __restrict__ W1, const float* __restrict__ W2,
    const float* __restrict__ Wihf, const float* __restrict__ Whhf,
    const float* __restrict__ Wihb, const float* __restrict__ Whhb,
    unsigned short* __restrict__ W1T, unsigned short* __restrict__ W2T,
    unsigned short* __restrict__ Wfx, unsigned short* __restrict__ Wfh,
    unsigned short* __restrict__ Wbx, unsigned short* __restrict__ Wbh)
{
  int i = blockIdx.x*256 + threadIdx.x;
  if (i < 32768){                 // W1 [512][64] -> W1T [64][512]
    int k = i >> 6, c = i & 63;
    W1T[c*512 + k] = f2bf(W1[i]);
  } else if (i < 36864){          // W2 [64][64] -> W2T [64][64]
    int j = i - 32768; int k = j >> 6, c = j & 63;
    W2T[c*64 + k] = f2bf(W2[j]);
  } else if (i < 102400){         // 4 x [256][64] straight bf16 copies
    int j = i - 36864;
    int which = j >> 14, o = j & 16383;
    const float* src = which==0 ? Wihf : which==1 ? Whhf : which==2 ? Wihb : Whhb;
    unsigned short* dst = which==0 ? Wfx : which==1 ? Wfh : which==2 ? Wbx : Wbh;
    dst[o] = f2bf(src[o]);
  }
}

// ================= layer-1 GEMM (K=512): double-buffered LDS staging ===============
// 64 rows/block; K-chunks of 64 f32 staged coalesced into padded LDS [64][68].
__global__ __launch_bounds__(256, 2) void k_gemm512(
    const float* __restrict__ Xf, const unsigned short* __restrict__ WT,
    const float* __restrict__ as_, const float* __restrict__ ad_,
    unsigned short* __restrict__ Hb, unsigned short* __restrict__ alsb,
    float* __restrict__ ald, int n)
{
  __shared__ float xs[2][64][68];          // 2 x 17408 B, pad 68 -> 2-way banks (free)
  int t = threadIdx.x;
  int w = t >> 6, l = t & 63;
  int c = l & 15, kg = l >> 4;
  int n0 = blockIdx.x*64;

  // staging role: thread t loads 64 B of row (t>>2), cols (t&3)*16 .. +15
  int sr = t >> 2;
  int sc = (t & 3) << 4;
  const float* srcrow = Xf + (size_t)min(n0 + sr, n-1)*512 + sc;
  const unsigned short* wpp = WT + (size_t)c*512 + kg*8;

  f32x4 acc[4];
  #pragma unroll
  for (int j = 0; j < 4; j++) acc[j] = (f32x4){0.f,0.f,0.f,0.f};

  // prologue: chunk0 -> lds[0]; chunk1 -> regs
  float4 R[2][4];
  #pragma unroll
  for (int q = 0; q < 4; q++){
    float4 v = *reinterpret_cast<const float4*>(srcrow + q*4);
    *reinterpret_cast<float4*>(&xs[0][sr][sc + q*4]) = v;
  }
  #pragma unroll
  for (int q = 0; q < 4; q++)
    R[1][q] = *reinterpret_cast<const float4*>(srcrow + 64 + q*4);
  __syncthreads();

  #pragma unroll
  for (int kt = 0; kt < 8; ++kt){
    // issue loads for chunk kt+2 (overlap with compute below)
    if (kt < 6){
      #pragma unroll
      for (int q = 0; q < 4; q++)
        R[kt & 1][q] = *reinterpret_cast<const float4*>(srcrow + (kt+2)*64 + q*4);
    }
    // compute chunk kt from xs[kt&1]
    #pragma unroll
    for (int s = 0; s < 2; s++){
      const float* xp = &xs[kt & 1][w*16 + c][s*32 + kg*8];
      float4 u0 = *reinterpret_cast<const float4*>(xp);
      float4 u1 = *reinterpret_cast<const float4*>(xp + 4);
      union { unsigned u[4]; bf16x8 v; } cc;
      cc.u[0] = cvtpk(u0.x, u0.y);
      cc.u[1] = cvtpk(u0.z, u0.w);
      cc.u[2] = cvtpk(u1.x, u1.y);
      cc.u[3] = cvtpk(u1.z, u1.w);
      #pragma unroll
      for (int j = 0; j < 4; j++){
        bf16x8 b = *reinterpret_cast<const bf16x8*>(wpp + j*8192 + kt*64 + s*32);
        acc[j] = mfma_bf16(cc.v, b, acc[j]);
      }
    }
    // write chunk kt+1 (loaded last iteration) into the other buffer
    if (kt < 7){
      #pragma unroll
      for (int q = 0; q < 4; q++)
        *reinterpret_cast<float4*>(&xs[(kt+1) & 1][sr][sc + q*4]) = R[(kt+1) & 1][q];
    }
    __syncthreads();
  }

  // epilogue: H store + per-head logits
  float asl[4], adl[4];
  #pragma unroll
  for (int j = 0; j < 4; j++){ asl[j] = as_[j*16 + c]; adl[j] = ad_[j*16 + c]; }
  #pragma unroll
  for (int j = 0; j < 4; j++){
    #pragma unroll
    for (int r = 0; r < 4; r++){
      int grow = n0 + w*16 + kg*4 + r;
      float v = acc[j][r];
      if (grow < n) Hb[(size_t)grow*64 + j*16 + c] = f2bf(v);
      float sv = v*asl[j];
      float dv = v*adl[j];
      sv += __shfl_xor(sv, 1, 64); sv += __shfl_xor(sv, 2, 64); sv += __shfl_xor(sv, 4, 64);
      dv += __shfl_xor(dv, 1, 64); dv += __shfl_xor(dv, 2, 64); dv += __shfl_xor(dv, 4, 64);
      if ((c & 7) == 0 && grow < n){
        int head = j*2 + (c >> 3);
        alsb[(size_t)grow*8 + head] = f2bf(sv);
        ald [(size_t)grow*8 + head] = dv;
      }
    }
  }
}

// ================= layer-2 GEMM (K=64, bf16 src) + logit epilogue =================
__global__ __launch_bounds__(256) void k_gemm64(
    const unsigned short* __restrict__ Xh, const unsigned short* __restrict__ WT,
    const float* __restrict__ as_, const float* __restrict__ ad_,
    unsigned short* __restrict__ Hb, unsigned short* __restrict__ alsb,
    float* __restrict__ ald, int n)
{
  int t = threadIdx.x;
  int w = t >> 6, l = t & 63;
  int c = l & 15, kg = l >> 4;
  int n0 = blockIdx.x*64 + w*16;
  int row = min(n0 + c, n-1);
  f32x4 acc[4];
  #pragma unroll
  for (int j = 0; j < 4; j++) acc[j] = (f32x4){0.f,0.f,0.f,0.f};

  #pragma unroll
  for (int kt = 0; kt < 2; ++kt){
    int ko = kt*32 + kg*8;
    bf16x8 a = *reinterpret_cast<const bf16x8*>(Xh + (size_t)row*64 + ko);
    #pragma unroll
    for (int j = 0; j < 4; j++){
      bf16x8 b = *reinterpret_cast<const bf16x8*>(WT + (size_t)(j*16 + c)*64 + ko);
      acc[j] = mfma_bf16(a, b, acc[j]);
    }
  }
  float asl[4], adl[4];
  #pragma unroll
  for (int j = 0; j < 4; j++){ asl[j] = as_[j*16 + c]; adl[j] = ad_[j*16 + c]; }
  #pragma unroll
  for (int j = 0; j < 4; j++){
    #pragma unroll
    for (int r = 0; r < 4; r++){
      int grow = n0 + kg*4 + r;
      float v = acc[j][r];
      if (grow < n) Hb[(size_t)grow*64 + j*16 + c] = f2bf(v);
      float sv = v*asl[j];
      float dv = v*adl[j];
      sv += __shfl_xor(sv, 1, 64); sv += __shfl_xor(sv, 2, 64); sv += __shfl_xor(sv, 4, 64);
      dv += __shfl_xor(dv, 1, 64); dv += __shfl_xor(dv, 2, 64); dv += __shfl_xor(dv, 4, 64);
      if ((c & 7) == 0 && grow < n){
        int head = j*2 + (c >> 3);
        alsb[(size_t)grow*8 + head] = f2bf(sv);
        ald [(size_t)grow*8 + head] = dv;
      }
    }
  }
}

// ================= GAT aggregation: 8 lanes/node, 8-deep edge pipeline =============
struct EdgeBuf {
  float a0, a1, a2, a3;
  uint4 h0, h1, h2, h3;
};

__device__ __forceinline__ void loadEB(EdgeBuf& b, const int* __restrict__ col,
                                       int pos, int beg, int end,
                                       const unsigned short* __restrict__ ap,
                                       const unsigned short* __restrict__ Hp){
  int s0 = (pos   < end) ? col[pos]   : col[beg];
  int s1 = (pos+1 < end) ? col[pos+1] : s0;
  int s2 = (pos+2 < end) ? col[pos+2] : s0;
  int s3 = (pos+3 < end) ? col[pos+3] : s0;
  b.a0 = bf2f(ap[s0*8]); b.a1 = bf2f(ap[s1*8]);
  b.a2 = bf2f(ap[s2*8]); b.a3 = bf2f(ap[s3*8]);
  b.h0 = *reinterpret_cast<const uint4*>(Hp + (size_t)s0*64);
  b.h1 = *reinterpret_cast<const uint4*>(Hp + (size_t)s1*64);
  b.h2 = *reinterpret_cast<const uint4*>(Hp + (size_t)s2*64);
  b.h3 = *reinterpret_cast<const uint4*>(Hp + (size_t)s3*64);
}

__device__ __forceinline__ void acc8(float (&acc)[8], float xf, uint4 g){
  acc[0] = fmaf(xf, bf2f((unsigned short)g.x), acc[0]);
  acc[1] = fmaf(xf, bf2f((unsigned short)(g.x>>16)), acc[1]);
  acc[2] = fmaf(xf, bf2f((unsigned short)g.y), acc[2]);
  acc[3] = fmaf(xf, bf2f((unsigned short)(g.y>>16)), acc[3]);
  acc[4] = fmaf(xf, bf2f((unsigned short)g.z), acc[4]);
  acc[5] = fmaf(xf, bf2f((unsigned short)(g.z>>16)), acc[5]);
  acc[6] = fmaf(xf, bf2f((unsigned short)g.w), acc[6]);
  acc[7] = fmaf(xf, bf2f((unsigned short)(g.w>>16)), acc[7]);
}

__device__ __forceinline__ void computeEB(const EdgeBuf& b, int pos, int end, float adv,
                                          float& ssum, float (&acc)[8]){
  float e0 = b.a0 + adv; e0 = (e0>0.f)?e0:0.2f*e0;
  float e1 = b.a1 + adv; e1 = (e1>0.f)?e1:0.2f*e1;
  float e2 = b.a2 + adv; e2 = (e2>0.f)?e2:0.2f*e2;
  float e3 = b.a3 + adv; e3 = (e3>0.f)?e3:0.2f*e3;
  float x0 = __expf(e0);
  float x1 = (pos+1 < end) ? __expf(e1) : 0.f;
  float x2 = (pos+2 < end) ? __expf(e2) : 0.f;
  float x3 = (pos+3 < end) ? __expf(e3) : 0.f;
  ssum += (x0 + x1) + (x2 + x3);
  acc8(acc, x0, b.h0);
  acc8(acc, x1, b.h1);
  acc8(acc, x2, b.h2);
  acc8(acc, x3, b.h3);
}

template<bool DO_ELU>
__global__ __launch_bounds__(256) void k_agg(
    const int* __restrict__ rowptr, const int* __restrict__ col,
    const unsigned short* __restrict__ Hb, const unsigned short* __restrict__ alsb,
    const float* __restrict__ ald, const float* __restrict__ bias,
    unsigned short* __restrict__ outb, int n)
{
  int grp = threadIdx.x >> 3;           // 32 node-groups per block
  int ln  = threadIdx.x & 7;            // lane owns head ln (8 channels)
  int node = blockIdx.x*32 + grp;
  if (node >= n) return;
  float adv = ald[node*8 + ln];
  int beg = rowptr[node], end = rowptr[node+1];
  const unsigned short* Hp = Hb + ln*8;
  const unsigned short* ap = alsb + ln;

  float acc[8];
  #pragma unroll
  for (int q = 0; q < 8; q++) acc[q] = 0.f;
  float ssum = 0.f;

  EdgeBuf A, B;
  int p = beg;
  loadEB(A, col, p,   beg, end, ap, Hp);
  loadEB(B, col, p+4, beg, end, ap, Hp);
  while (true){
    computeEB(A, p, end, adv, ssum, acc);
    if (p + 8 < end) loadEB(A, col, p+8, beg, end, ap, Hp);
    p += 4;
    if (p >= end) break;
    computeEB(B, p, end, adv, ssum, acc);
    if (p + 8 < end) loadEB(B, col, p+8, beg, end, ap, Hp);
    p += 4;
    if (p >= end) break;
  }

  float inv = 1.f/ssum;
  ushort4 pk0, pk1;
  float o[8];
  #pragma unroll
  for (int q = 0; q < 8; q++){
    o[q] = acc[q]*inv + bias[ln*8 + q];
    if (DO_ELU) o[q] = (o[q] > 0.f) ? o[q] : (__expf(o[q]) - 1.f);
  }
  pk0.x = f2bf(o[0]); pk0.y = f2bf(o[1]); pk0.z = f2bf(o[2]); pk0.w = f2bf(o[3]);
  pk1.x = f2bf(o[4]); pk1.y = f2bf(o[5]); pk1.z = f2bf(o[6]); pk1.w = f2bf(o[7]);
  *reinterpret_cast<ushort4*>(outb + (size_t)node*64 + ln*8)     = pk0;
  *reinterpret_cast<ushort4*>(outb + (size_t)node*64 + ln*8 + 4) = pk1;
}

// ================= fused bidirectional 2-step LSTM (one dispatch) =================
__global__ __launch_bounds__(256) void k_lstm(
    const unsigned short* __restrict__ X1b, const unsigned short* __restrict__ X2b,
    const unsigned short* __restrict__ Wfx, const unsigned short* __restrict__ Wfh,
    const unsigned short* __restrict__ Wbx, const unsigned short* __restrict__ Wbh,
    const float* __restrict__ bihf, const float* __restrict__ bhhf,
    const float* __restrict__ bihb, const float* __restrict__ bhhb,
    const float* __restrict__ watt,
    float* __restrict__ pf0, float* __restrict__ pf1,
    float* __restrict__ pb0, float* __restrict__ pb1, int n)
{
  int dir = blockIdx.y;
  const unsigned short* X0 = dir ? X2b : X1b;   // step0 input
  const unsigned short* X1 = dir ? X1b : X2b;   // step1 input
  const unsigned short* Wx = dir ? Wbx : Wfx;
  const unsigned short* Wh = dir ? Wbh : Wfh;
  const float* bi = dir ? bihb : bihf;
  const float* bh = dir ? bhhb : bhhf;
  const float* wa = watt + dir*64;
  float* po0 = dir ? pb0 : pf0;
  float* po1 = dir ? pb1 : pf1;

  __shared__ unsigned short hls[32][72];   // padded: b128 reads -> 2-way (free)
  __shared__ float attp[2][4][32];

  int t = threadIdx.x;
  int w = t >> 6, l = t & 63;
  int c = l & 15, kg = l >> 4;
  int n0 = blockIdx.x*32;
  int r0 = min(n0 + c, n-1);
  int r1 = min(n0 + 16 + c, n-1);

  int hid = w*16 + c;
  float bs0 = bi[hid]       + bh[hid];
  float bs1 = bi[hid + 64]  + bh[hid + 64];
  float bs2 = bi[hid + 128] + bh[hid + 128];
  float bs3 = bi[hid + 192] + bh[hid + 192];
  float wav = wa[hid];

  // ---- step 0: gates = X0 @ Wx^T ----
  f32x4 acc[2][4];
  #pragma unroll
  for (int m = 0; m < 2; m++)
    #pragma unroll
    for (int g = 0; g < 4; g++) acc[m][g] = (f32x4){0.f,0.f,0.f,0.f};

  #pragma unroll
  for (int kt = 0; kt < 2; ++kt){
    int ko = kt*32 + kg*8;
    bf16x8 a0 = *reinterpret_cast<const bf16x8*>(X0 + (size_t)r0*64 + ko);
    bf16x8 a1 = *reinterpret_cast<const bf16x8*>(X0 + (size_t)r1*64 + ko);
    #pragma unroll
    for (int g = 0; g < 4; g++){
      bf16x8 b = *reinterpret_cast<const bf16x8*>(Wx + (size_t)(g*64 + hid)*64 + ko);
      acc[0][g] = mfma_bf16(a0, b, acc[0][g]);
      acc[1][g] = mfma_bf16(a1, b, acc[1][g]);
    }
  }
  float creg[2][4];
  #pragma unroll
  for (int m = 0; m < 2; m++){
    #pragma unroll
    for (int r = 0; r < 4; r++){
      int rl = m*16 + kg*4 + r;
      float gi = acc[m][0][r] + bs0;
      float gg = acc[m][2][r] + bs2;
      float go = acc[m][3][r] + bs3;
      float cc = fsigm(gi)*ftanh(gg);
      float hh = fsigm(go)*ftanh(cc);
      creg[m][r] = cc;
      hls[rl][hid] = f2bf(hh);
      float s = hh*wav;
      s += __shfl_xor(s, 1, 16);
      s += __shfl_xor(s, 2, 16);
      s += __shfl_xor(s, 4, 16);
      s += __shfl_xor(s, 8, 16);
      if (c == 0) attp[0][w][rl] = s;
    }
  }
  __syncthreads();

  // ---- step 1: gates = X1 @ Wx^T + h0 @ Wh^T ----
  #pragma unroll
  for (int m = 0; m < 2; m++)
    #pragma unroll
    for (int g = 0; g < 4; g++) acc[m][g] = (f32x4){0.f,0.f,0.f,0.f};

  #pragma unroll
  for (int kt = 0; kt < 4; ++kt){
    int ko = (kt & 1)*32 + kg*8;
    bf16x8 a0, a1;
    if (kt < 2){
      a0 = *reinterpret_cast<const bf16x8*>(X1 + (size_t)r0*64 + ko);
      a1 = *reinterpret_cast<const bf16x8*>(X1 + (size_t)r1*64 + ko);
    } else {
      a0 = *reinterpret_cast<const bf16x8*>(&hls[c][ko]);
      a1 = *reinterpret_cast<const bf16x8*>(&hls[16 + c][ko]);
    }
    const unsigned short* Wp = (kt < 2) ? Wx : Wh;
    #pragma unroll
    for (int g = 0; g < 4; g++){
      bf16x8 b = *reinterpret_cast<const bf16x8*>(Wp + (size_t)(g*64 + hid)*64 + ko);
      acc[0][g] = mfma_bf16(a0, b, acc[0][g]);
      acc[1][g] = mfma_bf16(a1, b, acc[1][g]);
    }
  }
  #pragma unroll
  for (int m = 0; m < 2; m++){
    #pragma unroll
    for (int r = 0; r < 4; r++){
      int rl = m*16 + kg*4 + r;
      float gi = acc[m][0][r] + bs0;
      float gf = acc[m][1][r] + bs1;
      float gg = acc[m][2][r] + bs2;
      float go = acc[m][3][r] + bs3;
      float cc = fsigm(gf)*creg[m][r] + fsigm(gi)*ftanh(gg);
      float hh = fsigm(go)*ftanh(cc);
      float s = hh*wav;
      s += __shfl_xor(s, 1, 16);
      s += __shfl_xor(s, 2, 16);
      s += __shfl_xor(s, 4, 16);
      s += __shfl_xor(s, 8, 16);
      if (c == 0) attp[1][w][rl] = s;
    }
  }
  __syncthreads();
  if (t < 32){
    int grow = n0 + t;
    if (grow < n) po0[grow] = attp[0][0][t] + attp[0][1][t] + attp[0][2][t] + attp[0][3][t];
  } else if (t < 64){
    int rr = t - 32;
    int grow = n0 + rr;
    if (grow < n) po1[grow] = attp[1][0][rr] + attp[1][1][rr] + attp[1][2][rr] + attp[1][3][rr];
  }
}

// ================= JK attention + output GEMM + log_softmax =================
__global__ __launch_bounds__(256) void k_final(
    const unsigned short* __restrict__ x1b, const unsigned short* __restrict__ x2b,
    const float* __restrict__ pf0, const float* __restrict__ pf1,
    const float* __restrict__ pb0, const float* __restrict__ pb1,
    const float* __restrict__ Wout, float* __restrict__ out, int n)
{
  __shared__ __align__(16) float ws[NCLS][68];
  __shared__ __align__(16) float fs[32][68];
  int t = threadIdx.x;
  for (int i = t; i < NCLS*64; i += 256)
    ws[i>>6][i&63] = Wout[i];

  int n0 = blockIdx.x*32;
  int nd = t >> 3, q8 = t & 7;
  int g = n0 + nd;
  int eb = q8*8;
  if (g < n){
    float att0 = pf0[g] + pb1[g];
    float att1 = pf1[g] + pb0[g];
    float a0 = 1.f/(1.f + __expf(att1 - att0));
    float a1 = 1.f - a0;
    uint4 p1 = *reinterpret_cast<const uint4*>(x1b + (size_t)g*64 + eb);
    uint4 p2 = *reinterpret_cast<const uint4*>(x2b + (size_t)g*64 + eb);
    const unsigned* u1 = (const unsigned*)&p1;
    const unsigned* u2 = (const unsigned*)&p2;
    #pragma unroll
    for (int q = 0; q < 4; q++){
      float v1l = bf2f((unsigned short)u1[q]), v1h = bf2f((unsigned short)(u1[q]>>16));
      float v2l = bf2f((unsigned short)u2[q]), v2h = bf2f((unsigned short)(u2[q]>>16));
      fs[nd][eb + q*2 + 0] = a0*v1l + a1*v2l;
      fs[nd][eb + q*2 + 1] = a0*v1h + a1*v2h;
    }
  } else {
    #pragma unroll
    for (int q = 0; q < 8; q++) fs[nd][eb+q] = 0.f;
  }
  __syncthreads();

  float lg[5] = {0.f,0.f,0.f,0.f,0.f};
  #pragma unroll
  for (int k4 = 0; k4 < 16; k4++){
    float4 f = *reinterpret_cast<const float4*>(&fs[nd][k4*4]);
    #pragma unroll
    for (int q = 0; q < 5; q++){
      int cc = q8 + 8*q;
      float4 wv = *reinterpret_cast<const float4*>(&ws[cc][k4*4]);
      lg[q] = fmaf(f.x, wv.x, lg[q]);
      lg[q] = fmaf(f.y, wv.y, lg[q]);
      lg[q] = fmaf(f.z, wv.z, lg[q]);
      lg[q] = fmaf(f.w, wv.w, lg[q]);
    }
  }
  float mx = lg[0];
  #pragma unroll
  for (int q = 1; q < 5; q++) mx = fmaxf(mx, lg[q]);
  #pragma unroll
  for (int mk = 1; mk < 8; mk <<= 1) mx = fmaxf(mx, __shfl_xor(mx, mk, 64));
  float se = 0.f;
  #pragma unroll
  for (int q = 0; q < 5; q++) se += __expf(lg[q] - mx);
  #pragma unroll
  for (int mk = 1; mk < 8; mk <<= 1) se += __shfl_xor(se, mk, 64);
  float lse = __logf(se);
  if (g < n){
    #pragma unroll
    for (int q = 0; q < 5; q++)
      out[(size_t)g*NCLS + q8 + 8*q] = lg[q] - mx - lse;
  }
}

// ================= host =================
extern "C" void kernel_launch(void* const* d_in, const int* in_sizes, int n_in,
                              void* d_out, int out_size, void* d_ws, size_t ws_size,
                              hipStream_t stream)
{
  const float* x    = (const float*)d_in[0];
  const int*   ei   = (const int*)d_in[1];
  const float* W1   = (const float*)d_in[2];
  const float* a1s  = (const float*)d_in[3];
  const float* a1d  = (const float*)d_in[4];
  const float* b1   = (const float*)d_in[5];
  const float* W2   = (const float*)d_in[6];
  const float* a2s  = (const float*)d_in[7];
  const float* a2d  = (const float*)d_in[8];
  const float* b2   = (const float*)d_in[9];
  const float* Wih_f= (const float*)d_in[10];
  const float* Whh_f= (const float*)d_in[11];
  const float* bih_f= (const float*)d_in[12];
  const float* bhh_f= (const float*)d_in[13];
  const float* Wih_b= (const float*)d_in[14];
  const float* Whh_b= (const float*)d_in[15];
  const float* bih_b= (const float*)d_in[16];
  const float* bhh_b= (const float*)d_in[17];
  const float* watt = (const float*)d_in[18];
  const float* Wout = (const float*)d_in[20];
  float* out = (float*)d_out;

  int n = in_sizes[0] / F_IN;   // 100000
  int e = in_sizes[1] / 2;      // 1600000
  int nb = (n + BNODES - 1) >> BSH;       // buckets of 128 nodes (782)
  int B  = (e + n + CH - 1) / CH;         // partition blocks (~104)

  char* p = (char*)d_ws;
  auto alloc = [&](size_t b)->char*{ char* r = p; p += (b + 255) & ~(size_t)255; return r; };
  int* rowptr = (int*)alloc((size_t)(n+1)*4);
  int* colidx = (int*)alloc((size_t)(e+n)*4);
  unsigned* bedges = (unsigned*)alloc((size_t)(e+n)*4);
  int* bhist  = (int*)alloc((size_t)B*nb*4);
  int* bcnt   = (int*)alloc((size_t)(nb+1)*4);
  int* bbase  = (int*)alloc((size_t)(nb+1)*4);
  unsigned short* hbuf = (unsigned short*)alloc((size_t)n*64*2);   // bf16 H
  unsigned short* alsb = (unsigned short*)alloc((size_t)n*8*2);    // bf16 als
  float* ald  = (float*)alloc((size_t)n*8*4);
  unsigned short* x1b = (unsigned short*)alloc((size_t)n*64*2);
  unsigned short* x2b = (unsigned short*)alloc((size_t)n*64*2);
  float* pf0 = (float*)alloc((size_t)n*4);
  float* pf1 = (float*)alloc((size_t)n*4);
  float* pb0 = (float*)alloc((size_t)n*4);
  float* pb1 = (float*)alloc((size_t)n*4);
  unsigned short* W1T = (unsigned short*)alloc((size_t)64*512*2);
  unsigned short* W2T = (unsigned short*)alloc((size_t)64*64*2);
  unsigned short* Wfx = (unsigned short*)alloc((size_t)256*64*2);
  unsigned short* Wfh = (unsigned short*)alloc((size_t)256*64*2);
  unsigned short* Wbx = (unsigned short*)alloc((size_t)256*64*2);
  unsigned short* Wbh = (unsigned short*)alloc((size_t)256*64*2);

  // ---- CSR build (block-aggregated partition, no global atomics) ----
  k_pcount<<<B, 256, 0, stream>>>(ei, e, n, nb, bhist);
  k_pscan1<<<(nb+255)/256, 256, 0, stream>>>(bhist, nb, B, bcnt);
  k_pscan2<<<1, 256, 0, stream>>>(bcnt, nb, e+n, bbase, rowptr, n);
  k_pscatter<<<B, 256, 0, stream>>>(ei, e, n, nb, bhist, bbase, bedges);
  k_bbuild<<<nb, 256, 0, stream>>>(bedges, bbase, rowptr, colidx, n);

  // ---- weight conversion (single dispatch) ----
  k_prep<<<400, 256, 0, stream>>>(W1, W2, Wih_f, Whh_f, Wih_b, Whh_b,
                                  W1T, W2T, Wfx, Wfh, Wbx, Wbh);

  // ---- GAT layers (attention logits fused into GEMM epilogue) ----
  int gblk = (n + 63)/64;
  k_gemm512<<<gblk, 256, 0, stream>>>(x, W1T, a1s, a1d, hbuf, alsb, ald, n);
  k_agg<true ><<<(n+31)/32, 256, 0, stream>>>(rowptr, colidx, hbuf, alsb, ald, b1, x1b, n);
  k_gemm64<<<gblk, 256, 0, stream>>>(x1b, W2T, a2s, a2d, hbuf, alsb, ald, n);
  k_agg<false><<<(n+31)/32, 256, 0, stream>>>(rowptr, colidx, hbuf, alsb, ald, b2, x2b, n);

  // ---- JK LSTM: both directions, both steps, one dispatch ----
  dim3 lgrid((n + 31)/32, 2);
  k_lstm<<<lgrid, 256, 0, stream>>>(x1b, x2b, Wfx, Wfh, Wbx, Wbh,
                                    bih_f, bhh_f, bih_b, bhh_b,
                                    watt, pf0, pf1, pb0, pb1, n);

  // ---- output layer ----
  k_final<<<(n+3)/4, 256, 0, stream>>>(x1b, x2b, pf0, pf1, pb0, pb1, Wout, out, n);
}

// Round 12
// 504.676 us; speedup vs baseline: 1.0897x; 1.0897x over previous
//
#include <hip/hip_runtime.h>
#include <math.h>

#define F_IN 512
#define NCLS 40
#define BSH 7                 // 128 nodes per bucket
#define BNODES (1 << BSH)
#define CH 16384              // edges per partition block

typedef __attribute__((ext_vector_type(8))) short bf16x8;
typedef __attribute__((ext_vector_type(4))) float f32x4;

__device__ __forceinline__ f32x4 mfma_bf16(bf16x8 a, bf16x8 b, f32x4 c){
  return __builtin_amdgcn_mfma_f32_16x16x32_bf16(a, b, c, 0, 0, 0);
}
__device__ __forceinline__ float fsigm(float x){ return 1.f/(1.f+__expf(-x)); }
__device__ __forceinline__ float ftanh(float x){ return 1.f - 2.f/(__expf(2.f*x)+1.f); }
__device__ __forceinline__ unsigned short f2bf(float f){
  unsigned u = __float_as_uint(f);
  return (unsigned short)((u + 0x7fffu + ((u>>16)&1u)) >> 16);
}
__device__ __forceinline__ float bf2f(unsigned short h){
  return __uint_as_float(((unsigned)h) << 16);
}
// packed f32x2 -> bf16x2 (RTNE, HW instruction)
__device__ __forceinline__ unsigned cvtpk(float lo, float hi){
  unsigned r;
  asm("v_cvt_pk_bf16_f32 %0, %1, %2" : "=v"(r) : "v"(lo), "v"(hi));
  return r;
}

// ================= CSR build: block-aggregated partition (no global atomics) ========
__global__ __launch_bounds__(256) void k_pcount(const int* __restrict__ ei, int e, int n,
                                                int nb, int* __restrict__ bhist){
  __shared__ int h[1024];
  int b = blockIdx.x, t = threadIdx.x;
  for (int i = t; i < nb; i += 256) h[i] = 0;
  __syncthreads();
  int tot = e + n;
  int base = b*CH;
  int lim = min(base + CH, tot);
  for (int i = base + t; i < lim; i += 256){
    int d = (i < e) ? ei[e + i] : (i - e);
    atomicAdd(&h[d >> BSH], 1);
  }
  __syncthreads();
  for (int i = t; i < nb; i += 256) bhist[(size_t)b*nb + i] = h[i];
}

__global__ __launch_bounds__(256) void k_pscan1(int* __restrict__ bhist, int nb, int B,
                                                int* __restrict__ bcnt){
  int i = blockIdx.x*256 + threadIdx.x;
  if (i >= nb) return;
  int run = 0;
  for (int b = 0; b < B; b++){
    int v = bhist[(size_t)b*nb + i];
    bhist[(size_t)b*nb + i] = run;
    run += v;
  }
  bcnt[i] = run;
}

__global__ __launch_bounds__(256) void k_pscan2(const int* __restrict__ bcnt, int nb, int tot,
                                                int* __restrict__ bbase,
                                                int* __restrict__ rowptr, int n){
  __shared__ int sb[256];
  __shared__ int carry;
  int t = threadIdx.x;
  if (t == 0) carry = 0;
  __syncthreads();
  for (int c0 = 0; c0 < nb; c0 += 256){
    int v = (c0 + t < nb) ? bcnt[c0 + t] : 0;
    sb[t] = v; __syncthreads();
    for (int off = 1; off < 256; off <<= 1){
      int u = (t >= off) ? sb[t-off] : 0; __syncthreads();
      sb[t] += u; __syncthreads();
    }
    if (c0 + t < nb) bbase[c0 + t] = carry + sb[t] - v;
    __syncthreads();
    if (t == 0) carry += sb[255];
    __syncthreads();
  }
  if (t == 0){ bbase[nb] = carry; rowptr[n] = tot; }
}

__global__ __launch_bounds__(256) void k_pscatter(const int* __restrict__ ei, int e, int n,
                                                  int nb, const int* __restrict__ bhist,
                                                  const int* __restrict__ bbase,
                                                  unsigned* __restrict__ bedges){
  __shared__ int cur[1024];
  int b = blockIdx.x, t = threadIdx.x;
  for (int i = t; i < nb; i += 256)
    cur[i] = bbase[i] + bhist[(size_t)b*nb + i];
  __syncthreads();
  int tot = e + n;
  int base = b*CH;
  int lim = min(base + CH, tot);
  for (int i = base + t; i < lim; i += 256){
    int s, d;
    if (i < e){ s = ei[i]; d = ei[e + i]; } else { s = i - e; d = s; }
    int pos = atomicAdd(&cur[d >> BSH], 1);
    bedges[pos] = (unsigned)s | ((unsigned)(d & (BNODES-1)) << 20);
  }
}

__global__ __launch_bounds__(256) void k_bbuild(const unsigned* __restrict__ bedges,
                                                const int* __restrict__ bbase,
                                                int* __restrict__ rowptr, int* __restrict__ col, int n){
  int b = blockIdx.x;
  int t = threadIdx.x;
  __shared__ int hist[BNODES];
  __shared__ int sc[BNODES];
  __shared__ int cur[BNODES];
  int beg = bbase[b], end = bbase[b+1];
  if (t < BNODES) hist[t] = 0;
  __syncthreads();
  for (int i = beg + t; i < end; i += 256)
    atomicAdd(&hist[bedges[i] >> 20], 1);
  __syncthreads();
  int v = (t < BNODES) ? hist[t] : 0;
  if (t < BNODES) sc[t] = v;
  __syncthreads();
  for (int off = 1; off < BNODES; off <<= 1){
    int u = (t >= off && t < BNODES) ? sc[t-off] : 0;
    __syncthreads();
    if (t < BNODES) sc[t] += u;
    __syncthreads();
  }
  if (t < BNODES){
    int excl = sc[t] - v;
    int node = (b << BSH) + t;
    if (node < n) rowptr[node] = beg + excl;
    cur[t] = excl;
  }
  __syncthreads();
  for (int i = beg + t; i < end; i += 256){
    unsigned pk = bedges[i];
    int pos = atomicAdd(&cur[pk >> 20], 1);
    col[beg + pos] = (int)(pk & 0xFFFFFu);
  }
}

// ================= fused weight prep (all conversions, 1 dispatch) =================
__global__ __launch_bounds__(256) void k_prep(
    const float* __restrict__ W1, const float* __restrict__ W2,
    const float* __restrict__ Wihf, const float* __restrict__ Whhf,
    const float* __restrict__ Wihb, const float* __restrict__ Whhb,
    unsigned short* __restrict__ W1T, unsigned short* __restrict__ W2T,
    unsigned short* __restrict__ Wfx, unsigned short* __restrict__ Wfh,
    unsigned short* __restrict__ Wbx, unsigned short* __restrict__ Wbh)
{
  int i = blockIdx.x*256 + threadIdx.x;
  if (i < 32768){                 // W1 [512][64] -> W1T [64][512]
    int k = i >> 6, c = i & 63;
    W1T[c*512 + k] = f2bf(W1[i]);
  } else if (i < 36864){          // W2 [64][64] -> W2T [64][64]
    int j = i - 32768; int k = j >> 6, c = j & 63;
    W2T[c*64 + k] = f2bf(W2[j]);
  } else if (i < 102400){         // 4 x [256][64] straight bf16 copies
    int j = i - 36864;
    int which = j >> 14, o = j & 16383;
    const float* src = which==0 ? Wihf : which==1 ? Whhf : which==2 ? Wihb : Whhb;
    unsigned short* dst = which==0 ? Wfx : which==1 ? Wfh : which==2 ? Wbx : Wbh;
    dst[o] = f2bf(src[o]);
  }
}

// ================= layer-1 GEMM (K=512): decoupled stage->barrier->compute =========
// Stage: 16 independent 32B loads/thread (contiguous 128KB panel), cvtpk->bf16,
// XOR-swizzled 64KB LDS tile. One barrier. Compute: ds_read_b128 + MFMA, no barriers.
__global__ __launch_bounds__(256, 2) void k_gemm512(
    const float* __restrict__ Xf, const unsigned short* __restrict__ WT,
    const float* __restrict__ as_, const float* __restrict__ ad_,
    unsigned short* __restrict__ Hb, unsigned short* __restrict__ alsb,
    float* __restrict__ ald, int n)
{
  __shared__ unsigned short xs[64*512];   // 64 KB bf16, swizzled
  int t = threadIdx.x;
  int n0 = blockIdx.x*64;
  char* xsb = reinterpret_cast<char*>(xs);

  // ---- staging phase: block reads rows n0..n0+63 (128 KB) contiguously ----
  bool full = (n0 + 64 <= n);
  #pragma unroll
  for (int i = 0; i < 16; i++){
    int g  = i*256 + t;          // 32B-chunk index within panel
    int row = g >> 6;            // 64 chunks per 2KB row
    int ck  = g & 63;
    const float* src = full ? (Xf + (size_t)(n0 + row)*512 + ck*8)
                            : (Xf + (size_t)min(n0 + row, n-1)*512 + ck*8);
    float4 u0 = reinterpret_cast<const float4*>(src)[0];
    float4 u1 = reinterpret_cast<const float4*>(src)[1];
    uint4 pk;
    pk.x = cvtpk(u0.x, u0.y);
    pk.y = cvtpk(u0.z, u0.w);
    pk.z = cvtpk(u1.x, u1.y);
    pk.w = cvtpk(u1.z, u1.w);
    int byte = row*1024 + ((ck*16) ^ ((row & 7) << 4));
    *reinterpret_cast<uint4*>(xsb + byte) = pk;
  }
  __syncthreads();

  // ---- compute phase ----
  int w = t >> 6, l = t & 63;
  int c = l & 15, kg = l >> 4;
  int row = w*16 + c;
  const unsigned short* wp0 = WT + (size_t)c*512 + kg*8;

  f32x4 acc[4];
  #pragma unroll
  for (int j = 0; j < 4; j++) acc[j] = (f32x4){0.f,0.f,0.f,0.f};

  #pragma unroll
  for (int kt = 0; kt < 16; ++kt){
    int colb = (kt*64 + kg*16) ^ ((row & 7) << 4);
    bf16x8 a = *reinterpret_cast<const bf16x8*>(xsb + row*1024 + colb);
    #pragma unroll
    for (int j = 0; j < 4; j++){
      bf16x8 b = *reinterpret_cast<const bf16x8*>(wp0 + j*8192 + kt*32);
      acc[j] = mfma_bf16(a, b, acc[j]);
    }
  }

  // ---- epilogue: H store + per-head logits ----
  float asl[4], adl[4];
  #pragma unroll
  for (int j = 0; j < 4; j++){ asl[j] = as_[j*16 + c]; adl[j] = ad_[j*16 + c]; }
  #pragma unroll
  for (int j = 0; j < 4; j++){
    #pragma unroll
    for (int r = 0; r < 4; r++){
      int grow = n0 + w*16 + kg*4 + r;
      float v = acc[j][r];
      if (grow < n) Hb[(size_t)grow*64 + j*16 + c] = f2bf(v);
      float sv = v*asl[j];
      float dv = v*adl[j];
      sv += __shfl_xor(sv, 1, 64); sv += __shfl_xor(sv, 2, 64); sv += __shfl_xor(sv, 4, 64);
      dv += __shfl_xor(dv, 1, 64); dv += __shfl_xor(dv, 2, 64); dv += __shfl_xor(dv, 4, 64);
      if ((c & 7) == 0 && grow < n){
        int head = j*2 + (c >> 3);
        alsb[(size_t)grow*8 + head] = f2bf(sv);
        ald [(size_t)grow*8 + head] = dv;
      }
    }
  }
}

// ================= layer-2 GEMM (K=64, bf16 src) + logit epilogue =================
__global__ __launch_bounds__(256) void k_gemm64(
    const unsigned short* __restrict__ Xh, const unsigned short* __restrict__ WT,
    const float* __restrict__ as_, const float* __restrict__ ad_,
    unsigned short* __restrict__ Hb, unsigned short* __restrict__ alsb,
    float* __restrict__ ald, int n)
{
  int t = threadIdx.x;
  int w = t >> 6, l = t & 63;
  int c = l & 15, kg = l >> 4;
  int n0 = blockIdx.x*64 + w*16;
  int row = min(n0 + c, n-1);
  f32x4 acc[4];
  #pragma unroll
  for (int j = 0; j < 4; j++) acc[j] = (f32x4){0.f,0.f,0.f,0.f};

  #pragma unroll
  for (int kt = 0; kt < 2; ++kt){
    int ko = kt*32 + kg*8;
    bf16x8 a = *reinterpret_cast<const bf16x8*>(Xh + (size_t)row*64 + ko);
    #pragma unroll
    for (int j = 0; j < 4; j++){
      bf16x8 b = *reinterpret_cast<const bf16x8*>(WT + (size_t)(j*16 + c)*64 + ko);
      acc[j] = mfma_bf16(a, b, acc[j]);
    }
  }
  float asl[4], adl[4];
  #pragma unroll
  for (int j = 0; j < 4; j++){ asl[j] = as_[j*16 + c]; adl[j] = ad_[j*16 + c]; }
  #pragma unroll
  for (int j = 0; j < 4; j++){
    #pragma unroll
    for (int r = 0; r < 4; r++){
      int grow = n0 + kg*4 + r;
      float v = acc[j][r];
      if (grow < n) Hb[(size_t)grow*64 + j*16 + c] = f2bf(v);
      float sv = v*asl[j];
      float dv = v*adl[j];
      sv += __shfl_xor(sv, 1, 64); sv += __shfl_xor(sv, 2, 64); sv += __shfl_xor(sv, 4, 64);
      dv += __shfl_xor(dv, 1, 64); dv += __shfl_xor(dv, 2, 64); dv += __shfl_xor(dv, 4, 64);
      if ((c & 7) == 0 && grow < n){
        int head = j*2 + (c >> 3);
        alsb[(size_t)grow*8 + head] = f2bf(sv);
        ald [(size_t)grow*8 + head] = dv;
      }
    }
  }
}

// ================= GAT aggregation: 8 lanes/node, 8-deep edge pipeline =============
struct EdgeBuf {
  float a0, a1, a2, a3;
  uint4 h0, h1, h2, h3;
};

__device__ __forceinline__ void loadEB(EdgeBuf& b, const int* __restrict__ col,
                                       int pos, int beg, int end,
                                       const unsigned short* __restrict__ ap,
                                       const unsigned short* __restrict__ Hp){
  int s0 = (pos   < end) ? col[pos]   : col[beg];
  int s1 = (pos+1 < end) ? col[pos+1] : s0;
  int s2 = (pos+2 < end) ? col[pos+2] : s0;
  int s3 = (pos+3 < end) ? col[pos+3] : s0;
  b.a0 = bf2f(ap[s0*8]); b.a1 = bf2f(ap[s1*8]);
  b.a2 = bf2f(ap[s2*8]); b.a3 = bf2f(ap[s3*8]);
  b.h0 = *reinterpret_cast<const uint4*>(Hp + (size_t)s0*64);
  b.h1 = *reinterpret_cast<const uint4*>(Hp + (size_t)s1*64);
  b.h2 = *reinterpret_cast<const uint4*>(Hp + (size_t)s2*64);
  b.h3 = *reinterpret_cast<const uint4*>(Hp + (size_t)s3*64);
}

__device__ __forceinline__ void acc8(float (&acc)[8], float xf, uint4 g){
  acc[0] = fmaf(xf, bf2f((unsigned short)g.x), acc[0]);
  acc[1] = fmaf(xf, bf2f((unsigned short)(g.x>>16)), acc[1]);
  acc[2] = fmaf(xf, bf2f((unsigned short)g.y), acc[2]);
  acc[3] = fmaf(xf, bf2f((unsigned short)(g.y>>16)), acc[3]);
  acc[4] = fmaf(xf, bf2f((unsigned short)g.z), acc[4]);
  acc[5] = fmaf(xf, bf2f((unsigned short)(g.z>>16)), acc[5]);
  acc[6] = fmaf(xf, bf2f((unsigned short)g.w), acc[6]);
  acc[7] = fmaf(xf, bf2f((unsigned short)(g.w>>16)), acc[7]);
}

__device__ __forceinline__ void computeEB(const EdgeBuf& b, int pos, int end, float adv,
                                          float& ssum, float (&acc)[8]){
  float e0 = b.a0 + adv; e0 = (e0>0.f)?e0:0.2f*e0;
  float e1 = b.a1 + adv; e1 = (e1>0.f)?e1:0.2f*e1;
  float e2 = b.a2 + adv; e2 = (e2>0.f)?e2:0.2f*e2;
  float e3 = b.a3 + adv; e3 = (e3>0.f)?e3:0.2f*e3;
  float x0 = __expf(e0);
  float x1 = (pos+1 < end) ? __expf(e1) : 0.f;
  float x2 = (pos+2 < end) ? __expf(e2) : 0.f;
  float x3 = (pos+3 < end) ? __expf(e3) : 0.f;
  ssum += (x0 + x1) + (x2 + x3);
  acc8(acc, x0, b.h0);
  acc8(acc, x1, b.h1);
  acc8(acc, x2, b.h2);
  acc8(acc, x3, b.h3);
}

template<bool DO_ELU>
__global__ __launch_bounds__(256) void k_agg(
    const int* __restrict__ rowptr, const int* __restrict__ col,
    const unsigned short* __restrict__ Hb, const unsigned short* __restrict__ alsb,
    const float* __restrict__ ald, const float* __restrict__ bias,
    unsigned short* __restrict__ outb, int n)
{
  int grp = threadIdx.x >> 3;           // 32 node-groups per block
  int ln  = threadIdx.x & 7;            // lane owns head ln (8 channels)
  int node = blockIdx.x*32 + grp;
  if (node >= n) return;
  float adv = ald[node*8 + ln];
  int beg = rowptr[node], end = rowptr[node+1];
  const unsigned short* Hp = Hb + ln*8;
  const unsigned short* ap = alsb + ln;

  float acc[8];
  #pragma unroll
  for (int q = 0; q < 8; q++) acc[q] = 0.f;
  float ssum = 0.f;

  EdgeBuf A, B;
  int p = beg;
  loadEB(A, col, p,   beg, end, ap, Hp);
  loadEB(B, col, p+4, beg, end, ap, Hp);
  while (true){
    computeEB(A, p, end, adv, ssum, acc);
    if (p + 8 < end) loadEB(A, col, p+8, beg, end, ap, Hp);
    p += 4;
    if (p >= end) break;
    computeEB(B, p, end, adv, ssum, acc);
    if (p + 8 < end) loadEB(B, col, p+8, beg, end, ap, Hp);
    p += 4;
    if (p >= end) break;
  }

  float inv = 1.f/ssum;
  ushort4 pk0, pk1;
  float o[8];
  #pragma unroll
  for (int q = 0; q < 8; q++){
    o[q] = acc[q]*inv + bias[ln*8 + q];
    if (DO_ELU) o[q] = (o[q] > 0.f) ? o[q] : (__expf(o[q]) - 1.f);
  }
  pk0.x = f2bf(o[0]); pk0.y = f2bf(o[1]); pk0.z = f2bf(o[2]); pk0.w = f2bf(o[3]);
  pk1.x = f2bf(o[4]); pk1.y = f2bf(o[5]); pk1.z = f2bf(o[6]); pk1.w = f2bf(o[7]);
  *reinterpret_cast<ushort4*>(outb + (size_t)node*64 + ln*8)     = pk0;
  *reinterpret_cast<ushort4*>(outb + (size_t)node*64 + ln*8 + 4) = pk1;
}

// ================= fused bidirectional 2-step LSTM (one dispatch) =================
__global__ __launch_bounds__(256) void k_lstm(
    const unsigned short* __restrict__ X1b, const unsigned short* __restrict__ X2b,
    const unsigned short* __restrict__ Wfx, const unsigned short* __restrict__ Wfh,
    const unsigned short* __restrict__ Wbx, const unsigned short* __restrict__ Wbh,
    const float* __restrict__ bihf, const float* __restrict__ bhhf,
    const float* __restrict__ bihb, const float* __restrict__ bhhb,
    const float* __restrict__ watt,
    float* __restrict__ pf0, float* __restrict__ pf1,
    float* __restrict__ pb0, float* __restrict__ pb1, int n)
{
  int dir = blockIdx.y;
  const unsigned short* X0 = dir ? X2b : X1b;   // step0 input
  const unsigned short* X1 = dir ? X1b : X2b;   // step1 input
  const unsigned short* Wx = dir ? Wbx : Wfx;
  const unsigned short* Wh = dir ? Wbh : Wfh;
  const float* bi = dir ? bihb : bihf;
  const float* bh = dir ? bhhb : bhhf;
  const float* wa = watt + dir*64;
  float* po0 = dir ? pb0 : pf0;
  float* po1 = dir ? pb1 : pf1;

  __shared__ unsigned short hls[32][72];   // padded: b128 reads -> 2-way (free)
  __shared__ float attp[2][4][32];

  int t = threadIdx.x;
  int w = t >> 6, l = t & 63;
  int c = l & 15, kg = l >> 4;
  int n0 = blockIdx.x*32;
  int r0 = min(n0 + c, n-1);
  int r1 = min(n0 + 16 + c, n-1);

  int hid = w*16 + c;
  float bs0 = bi[hid]       + bh[hid];
  float bs1 = bi[hid + 64]  + bh[hid + 64];
  float bs2 = bi[hid + 128] + bh[hid + 128];
  float bs3 = bi[hid + 192] + bh[hid + 192];
  float wav = wa[hid];

  // ---- step 0: gates = X0 @ Wx^T ----
  f32x4 acc[2][4];
  #pragma unroll
  for (int m = 0; m < 2; m++)
    #pragma unroll
    for (int g = 0; g < 4; g++) acc[m][g] = (f32x4){0.f,0.f,0.f,0.f};

  #pragma unroll
  for (int kt = 0; kt < 2; ++kt){
    int ko = kt*32 + kg*8;
    bf16x8 a0 = *reinterpret_cast<const bf16x8*>(X0 + (size_t)r0*64 + ko);
    bf16x8 a1 = *reinterpret_cast<const bf16x8*>(X0 + (size_t)r1*64 + ko);
    #pragma unroll
    for (int g = 0; g < 4; g++){
      bf16x8 b = *reinterpret_cast<const bf16x8*>(Wx + (size_t)(g*64 + hid)*64 + ko);
      acc[0][g] = mfma_bf16(a0, b, acc[0][g]);
      acc[1][g] = mfma_bf16(a1, b, acc[1][g]);
    }
  }
  float creg[2][4];
  #pragma unroll
  for (int m = 0; m < 2; m++){
    #pragma unroll
    for (int r = 0; r < 4; r++){
      int rl = m*16 + kg*4 + r;
      float gi = acc[m][0][r] + bs0;
      float gg = acc[m][2][r] + bs2;
      float go = acc[m][3][r] + bs3;
      float cc = fsigm(gi)*ftanh(gg);
      float hh = fsigm(go)*ftanh(cc);
      creg[m][r] = cc;
      hls[rl][hid] = f2bf(hh);
      float s = hh*wav;
      s += __shfl_xor(s, 1, 16);
      s += __shfl_xor(s, 2, 16);
      s += __shfl_xor(s, 4, 16);
      s += __shfl_xor(s, 8, 16);
      if (c == 0) attp[0][w][rl] = s;
    }
  }
  __syncthreads();

  // ---- step 1: gates = X1 @ Wx^T + h0 @ Wh^T ----
  #pragma unroll
  for (int m = 0; m < 2; m++)
    #pragma unroll
    for (int g = 0; g < 4; g++) acc[m][g] = (f32x4){0.f,0.f,0.f,0.f};

  #pragma unroll
  for (int kt = 0; kt < 4; ++kt){
    int ko = (kt & 1)*32 + kg*8;
    bf16x8 a0, a1;
    if (kt < 2){
      a0 = *reinterpret_cast<const bf16x8*>(X1 + (size_t)r0*64 + ko);
      a1 = *reinterpret_cast<const bf16x8*>(X1 + (size_t)r1*64 + ko);
    } else {
      a0 = *reinterpret_cast<const bf16x8*>(&hls[c][ko]);
      a1 = *reinterpret_cast<const bf16x8*>(&hls[16 + c][ko]);
    }
    const unsigned short* Wp = (kt < 2) ? Wx : Wh;
    #pragma unroll
    for (int g = 0; g < 4; g++){
      bf16x8 b = *reinterpret_cast<const bf16x8*>(Wp + (size_t)(g*64 + hid)*64 + ko);
      acc[0][g] = mfma_bf16(a0, b, acc[0][g]);
      acc[1][g] = mfma_bf16(a1, b, acc[1][g]);
    }
  }
  #pragma unroll
  for (int m = 0; m < 2; m++){
    #pragma unroll
    for (int r = 0; r < 4; r++){
      int rl = m*16 + kg*4 + r;
      float gi = acc[m][0][r] + bs0;
      float gf = acc[m][1][r] + bs1;
      float gg = acc[m][2][r] + bs2;
      float go = acc[m][3][r] + bs3;
      float cc = fsigm(gf)*creg[m][r] + fsigm(gi)*ftanh(gg);
      float hh = fsigm(go)*ftanh(cc);
      float s = hh*wav;
      s += __shfl_xor(s, 1, 16);
      s += __shfl_xor(s, 2, 16);
      s += __shfl_xor(s, 4, 16);
      s += __shfl_xor(s, 8, 16);
      if (c == 0) attp[1][w][rl] = s;
    }
  }
  __syncthreads();
  if (t < 32){
    int grow = n0 + t;
    if (grow < n) po0[grow] = attp[0][0][t] + attp[0][1][t] + attp[0][2][t] + attp[0][3][t];
  } else if (t < 64){
    int rr = t - 32;
    int grow = n0 + rr;
    if (grow < n) po1[grow] = attp[1][0][rr] + attp[1][1][rr] + attp[1][2][rr] + attp[1][3][rr];
  }
}

// ================= JK attention + output GEMM + log_softmax =================
__global__ __launch_bounds__(256) void k_final(
    const unsigned short* __restrict__ x1b, const unsigned short* __restrict__ x2b,
    const float* __restrict__ pf0, const float* __restrict__ pf1,
    const float* __restrict__ pb0, const float* __restrict__ pb1,
    const float* __restrict__ Wout, float* __restrict__ out, int n)
{
  __shared__ __align__(16) float ws[NCLS][68];
  __shared__ __align__(16) float fs[32][68];
  int t = threadIdx.x;
  for (int i = t; i < NCLS*64; i += 256)
    ws[i>>6][i&63] = Wout[i];

  int n0 = blockIdx.x*32;
  int nd = t >> 3, q8 = t & 7;
  int g = n0 + nd;
  int eb = q8*8;
  if (g < n){
    float att0 = pf0[g] + pb1[g];
    float att1 = pf1[g] + pb0[g];
    float a0 = 1.f/(1.f + __expf(att1 - att0));
    float a1 = 1.f - a0;
    uint4 p1 = *reinterpret_cast<const uint4*>(x1b + (size_t)g*64 + eb);
    uint4 p2 = *reinterpret_cast<const uint4*>(x2b + (size_t)g*64 + eb);
    const unsigned* u1 = (const unsigned*)&p1;
    const unsigned* u2 = (const unsigned*)&p2;
    #pragma unroll
    for (int q = 0; q < 4; q++){
      float v1l = bf2f((unsigned short)u1[q]), v1h = bf2f((unsigned short)(u1[q]>>16));
      float v2l = bf2f((unsigned short)u2[q]), v2h = bf2f((unsigned short)(u2[q]>>16));
      fs[nd][eb + q*2 + 0] = a0*v1l + a1*v2l;
      fs[nd][eb + q*2 + 1] = a0*v1h + a1*v2h;
    }
  } else {
    #pragma unroll
    for (int q = 0; q < 8; q++) fs[nd][eb+q] = 0.f;
  }
  __syncthreads();

  float lg[5] = {0.f,0.f,0.f,0.f,0.f};
  #pragma unroll
  for (int k4 = 0; k4 < 16; k4++){
    float4 f = *reinterpret_cast<const float4*>(&fs[nd][k4*4]);
    #pragma unroll
    for (int q = 0; q < 5; q++){
      int cc = q8 + 8*q;
      float4 wv = *reinterpret_cast<const float4*>(&ws[cc][k4*4]);
      lg[q] = fmaf(f.x, wv.x, lg[q]);
      lg[q] = fmaf(f.y, wv.y, lg[q]);
      lg[q] = fmaf(f.z, wv.z, lg[q]);
      lg[q] = fmaf(f.w, wv.w, lg[q]);
    }
  }
  float mx = lg[0];
  #pragma unroll
  for (int q = 1; q < 5; q++) mx = fmaxf(mx, lg[q]);
  #pragma unroll
  for (int mk = 1; mk < 8; mk <<= 1) mx = fmaxf(mx, __shfl_xor(mx, mk, 64));
  float se = 0.f;
  #pragma unroll
  for (int q = 0; q < 5; q++) se += __expf(lg[q] - mx);
  #pragma unroll
  for (int mk = 1; mk < 8; mk <<= 1) se += __shfl_xor(se, mk, 64);
  float lse = __logf(se);
  if (g < n){
    #pragma unroll
    for (int q = 0; q < 5; q++)
      out[(size_t)g*NCLS + q8 + 8*q] = lg[q] - mx - lse;
  }
}

// ================= host =================
extern "C" void kernel_launch(void* const* d_in, const int* in_sizes, int n_in,
                              void* d_out, int out_size, void* d_ws, size_t ws_size,
                              hipStream_t stream)
{
  const float* x    = (const float*)d_in[0];
  const int*   ei   = (const int*)d_in[1];
  const float* W1   = (const float*)d_in[2];
  const float* a1s  = (const float*)d_in[3];
  const float* a1d  = (const float*)d_in[4];
  const float* b1   = (const float*)d_in[5];
  const float* W2   = (const float*)d_in[6];
  const float* a2s  = (const float*)d_in[7];
  const float* a2d  = (const float*)d_in[8];
  const float* b2   = (const float*)d_in[9];
  const float* Wih_f= (const float*)d_in[10];
  const float* Whh_f= (const float*)d_in[11];
  const float* bih_f= (const float*)d_in[12];
  const float* bhh_f= (const float*)d_in[13];
  const float* Wih_b= (const float*)d_in[14];
  const float* Whh_b= (const float*)d_in[15];
  const float* bih_b= (const float*)d_in[16];
  const float* bhh_b= (const float*)d_in[17];
  const float* watt = (const float*)d_in[18];
  const float* Wout = (const float*)d_in[20];
  float* out = (float*)d_out;

  int n = in_sizes[0] / F_IN;   // 100000
  int e = in_sizes[1] / 2;      // 1600000
  int nb = (n + BNODES - 1) >> BSH;       // buckets of 128 nodes (782)
  int B  = (e + n + CH - 1) / CH;         // partition blocks (~104)

  char* p = (char*)d_ws;
  auto alloc = [&](size_t b)->char*{ char* r = p; p += (b + 255) & ~(size_t)255; return r; };
  int* rowptr = (int*)alloc((size_t)(n+1)*4);
  int* colidx = (int*)alloc((size_t)(e+n)*4);
  unsigned* bedges = (unsigned*)alloc((size_t)(e+n)*4);
  int* bhist  = (int*)alloc((size_t)B*nb*4);
  int* bcnt   = (int*)alloc((size_t)(nb+1)*4);
  int* bbase  = (int*)alloc((size_t)(nb+1)*4);
  unsigned short* hbuf = (unsigned short*)alloc((size_t)n*64*2);   // bf16 H
  unsigned short* alsb = (unsigned short*)alloc((size_t)n*8*2);    // bf16 als
  float* ald  = (float*)alloc((size_t)n*8*4);
  unsigned short* x1b = (unsigned short*)alloc((size_t)n*64*2);
  unsigned short* x2b = (unsigned short*)alloc((size_t)n*64*2);
  float* pf0 = (float*)alloc((size_t)n*4);
  float* pf1 = (float*)alloc((size_t)n*4);
  float* pb0 = (float*)alloc((size_t)n*4);
  float* pb1 = (float*)alloc((size_t)n*4);
  unsigned short* W1T = (unsigned short*)alloc((size_t)64*512*2);
  unsigned short* W2T = (unsigned short*)alloc((size_t)64*64*2);
  unsigned short* Wfx = (unsigned short*)alloc((size_t)256*64*2);
  unsigned short* Wfh = (unsigned short*)alloc((size_t)256*64*2);
  unsigned short* Wbx = (unsigned short*)alloc((size_t)256*64*2);
  unsigned short* Wbh = (unsigned short*)alloc((size_t)256*64*2);

  // ---- CSR build (block-aggregated partition, no global atomics) ----
  k_pcount<<<B, 256, 0, stream>>>(ei, e, n, nb, bhist);
  k_pscan1<<<(nb+255)/256, 256, 0, stream>>>(bhist, nb, B, bcnt);
  k_pscan2<<<1, 256, 0, stream>>>(bcnt, nb, e+n, bbase, rowptr, n);
  k_pscatter<<<B, 256, 0, stream>>>(ei, e, n, nb, bhist, bbase, bedges);
  k_bbuild<<<nb, 256, 0, stream>>>(bedges, bbase, rowptr, colidx, n);

  // ---- weight conversion (single dispatch) ----
  k_prep<<<400, 256, 0, stream>>>(W1, W2, Wih_f, Whh_f, Wih_b, Whh_b,
                                  W1T, W2T, Wfx, Wfh, Wbx, Wbh);

  // ---- GAT layers (attention logits fused into GEMM epilogue) ----
  int gblk = (n + 63)/64;
  k_gemm512<<<gblk, 256, 0, stream>>>(x, W1T, a1s, a1d, hbuf, alsb, ald, n);
  k_agg<true ><<<(n+31)/32, 256, 0, stream>>>(rowptr, colidx, hbuf, alsb, ald, b1, x1b, n);
  k_gemm64<<<gblk, 256, 0, stream>>>(x1b, W2T, a2s, a2d, hbuf, alsb, ald, n);
  k_agg<false><<<(n+31)/32, 256, 0, stream>>>(rowptr, colidx, hbuf, alsb, ald, b2, x2b, n);

  // ---- JK LSTM: both directions, both steps, one dispatch ----
  dim3 lgrid((n + 31)/32, 2);
  k_lstm<<<lgrid, 256, 0, stream>>>(x1b, x2b, Wfx, Wfh, Wbx, Wbh,
                                    bih_f, bhh_f, bih_b, bhh_b,
                                    watt, pf0, pf1, pb0, pb1, n);

  // ---- output layer ----
  k_final<<<(n+3)/4, 256, 0, stream>>>(x1b, x2b, pf0, pf1, pb0, pb1, Wout, out, n);
}

// Round 13
// 493.401 us; speedup vs baseline: 1.1146x; 1.0229x over previous
//
#include <hip/hip_runtime.h>
#include <math.h>

#define F_IN 512
#define NCLS 40
#define BSH 7                 // 128 nodes per bucket
#define BNODES (1 << BSH)
#define CH 16384              // edges per partition block

typedef __attribute__((ext_vector_type(8))) short bf16x8;
typedef __attribute__((ext_vector_type(4))) float f32x4;

__device__ __forceinline__ f32x4 mfma_bf16(bf16x8 a, bf16x8 b, f32x4 c){
  return __builtin_amdgcn_mfma_f32_16x16x32_bf16(a, b, c, 0, 0, 0);
}
__device__ __forceinline__ float fsigm(float x){ return 1.f/(1.f+__expf(-x)); }
__device__ __forceinline__ float ftanh(float x){ return 1.f - 2.f/(__expf(2.f*x)+1.f); }
__device__ __forceinline__ unsigned short f2bf(float f){
  unsigned u = __float_as_uint(f);
  return (unsigned short)((u + 0x7fffu + ((u>>16)&1u)) >> 16);
}
__device__ __forceinline__ float bf2f(unsigned short h){
  return __uint_as_float(((unsigned)h) << 16);
}
// packed f32x2 -> bf16x2 (RTNE, HW instruction)
__device__ __forceinline__ unsigned cvtpk(float lo, float hi){
  unsigned r;
  asm("v_cvt_pk_bf16_f32 %0, %1, %2" : "=v"(r) : "v"(lo), "v"(hi));
  return r;
}

// ================= CSR build: block-aggregated partition (no global atomics) ========
__global__ __launch_bounds__(256) void k_pcount(const int* __restrict__ ei, int e, int n,
                                                int nb, int* __restrict__ bhist){
  __shared__ int h[1024];
  int b = blockIdx.x, t = threadIdx.x;
  for (int i = t; i < nb; i += 256) h[i] = 0;
  __syncthreads();
  int tot = e + n;
  int base = b*CH;
  int lim = min(base + CH, tot);
  for (int i = base + t; i < lim; i += 256){
    int d = (i < e) ? ei[e + i] : (i - e);
    atomicAdd(&h[d >> BSH], 1);
  }
  __syncthreads();
  for (int i = t; i < nb; i += 256) bhist[(size_t)b*nb + i] = h[i];
}

__global__ __launch_bounds__(256) void k_pscan1(int* __restrict__ bhist, int nb, int B,
                                                int* __restrict__ bcnt){
  int i = blockIdx.x*256 + threadIdx.x;
  if (i >= nb) return;
  int run = 0;
  for (int b = 0; b < B; b++){
    int v = bhist[(size_t)b*nb + i];
    bhist[(size_t)b*nb + i] = run;
    run += v;
  }
  bcnt[i] = run;
}

__global__ __launch_bounds__(256) void k_pscan2(const int* __restrict__ bcnt, int nb, int tot,
                                                int* __restrict__ bbase,
                                                int* __restrict__ rowptr, int n){
  __shared__ int sb[256];
  __shared__ int carry;
  int t = threadIdx.x;
  if (t == 0) carry = 0;
  __syncthreads();
  for (int c0 = 0; c0 < nb; c0 += 256){
    int v = (c0 + t < nb) ? bcnt[c0 + t] : 0;
    sb[t] = v; __syncthreads();
    for (int off = 1; off < 256; off <<= 1){
      int u = (t >= off) ? sb[t-off] : 0; __syncthreads();
      sb[t] += u; __syncthreads();
    }
    if (c0 + t < nb) bbase[c0 + t] = carry + sb[t] - v;
    __syncthreads();
    if (t == 0) carry += sb[255];
    __syncthreads();
  }
  if (t == 0){ bbase[nb] = carry; rowptr[n] = tot; }
}

__global__ __launch_bounds__(256) void k_pscatter(const int* __restrict__ ei, int e, int n,
                                                  int nb, const int* __restrict__ bhist,
                                                  const int* __restrict__ bbase,
                                                  unsigned* __restrict__ bedges){
  __shared__ int cur[1024];
  int b = blockIdx.x, t = threadIdx.x;
  for (int i = t; i < nb; i += 256)
    cur[i] = bbase[i] + bhist[(size_t)b*nb + i];
  __syncthreads();
  int tot = e + n;
  int base = b*CH;
  int lim = min(base + CH, tot);
  for (int i = base + t; i < lim; i += 256){
    int s, d;
    if (i < e){ s = ei[i]; d = ei[e + i]; } else { s = i - e; d = s; }
    int pos = atomicAdd(&cur[d >> BSH], 1);
    bedges[pos] = (unsigned)s | ((unsigned)(d & (BNODES-1)) << 20);
  }
}

__global__ __launch_bounds__(256) void k_bbuild(const unsigned* __restrict__ bedges,
                                                const int* __restrict__ bbase,
                                                int* __restrict__ rowptr, int* __restrict__ col, int n){
  int b = blockIdx.x;
  int t = threadIdx.x;
  __shared__ int hist[BNODES];
  __shared__ int sc[BNODES];
  __shared__ int cur[BNODES];
  int beg = bbase[b], end = bbase[b+1];
  if (t < BNODES) hist[t] = 0;
  __syncthreads();
  for (int i = beg + t; i < end; i += 256)
    atomicAdd(&hist[bedges[i] >> 20], 1);
  __syncthreads();
  int v = (t < BNODES) ? hist[t] : 0;
  if (t < BNODES) sc[t] = v;
  __syncthreads();
  for (int off = 1; off < BNODES; off <<= 1){
    int u = (t >= off && t < BNODES) ? sc[t-off] : 0;
    __syncthreads();
    if (t < BNODES) sc[t] += u;
    __syncthreads();
  }
  if (t < BNODES){
    int excl = sc[t] - v;
    int node = (b << BSH) + t;
    if (node < n) rowptr[node] = beg + excl;
    cur[t] = excl;
  }
  __syncthreads();
  for (int i = beg + t; i < end; i += 256){
    unsigned pk = bedges[i];
    int pos = atomicAdd(&cur[pk >> 20], 1);
    col[beg + pos] = (int)(pk & 0xFFFFFu);
  }
}

// ================= fused weight prep (all conversions, 1 dispatch) =================
__global__ __launch_bounds__(256) void k_prep(
    const float* __restrict__ W1, const float* __restrict__ W2,
    const float* __restrict__ Wihf, const float* __restrict__ Whhf,
    const float* __restrict__ Wihb, const float* __restrict__ Whhb,
    unsigned short* __restrict__ W1T, unsigned short* __restrict__ W2T,
    unsigned short* __restrict__ Wfx, unsigned short* __restrict__ Wfh,
    unsigned short* __restrict__ Wbx, unsigned short* __restrict__ Wbh)
{
  int i = blockIdx.x*256 + threadIdx.x;
  if (i < 32768){                 // W1 [512][64] -> W1T [64][512]
    int k = i >> 6, c = i & 63;
    W1T[c*512 + k] = f2bf(W1[i]);
  } else if (i < 36864){          // W2 [64][64] -> W2T [64][64]
    int j = i - 32768; int k = j >> 6, c = j & 63;
    W2T[c*64 + k] = f2bf(W2[j]);
  } else if (i < 102400){         // 4 x [256][64] straight bf16 copies
    int j = i - 36864;
    int which = j >> 14, o = j & 16383;
    const float* src = which==0 ? Wihf : which==1 ? Whhf : which==2 ? Wihb : Whhb;
    unsigned short* dst = which==0 ? Wfx : which==1 ? Wfh : which==2 ? Wbx : Wbh;
    dst[o] = f2bf(src[o]);
  }
}

// ================= layer-1 GEMM (K=512): async global_load_lds staging =============
// 1 wave / block, 16 rows, 32KB f32 LDS. Stage: 32 async DMA loads (16B each,
// source pre-swizzled so LDS lands XOR-swizzled). One barrier. Compute:
// ds_read_b128 pairs (same XOR) -> cvtpk -> MFMA. Logits moved to k_att.
__global__ __launch_bounds__(64) void k_gemm512(
    const float* __restrict__ Xf, const unsigned short* __restrict__ WT,
    unsigned short* __restrict__ Hb, int n)
{
  __shared__ float xs[16*512];     // 32 KB
  int l = threadIdx.x;             // 0..63
  int n0 = blockIdx.x*16;

  // ---- staging: 32 async DMAs; instruction j covers half-row (r = j>>1, h = j&1)
  #pragma unroll
  for (int j = 0; j < 32; j++){
    int r = j >> 1, h = j & 1;
    int rg = min(n0 + r, n-1);
    int sb = (l*16) ^ ((r & 7) << 4);                 // swizzled byte within half
    const float* g = Xf + (size_t)rg*512 + h*256 + (sb >> 2);
    float* lds = xs + r*512 + h*256;                  // wave-uniform base (+lane*16 by HW)
    __builtin_amdgcn_global_load_lds(
        (const __attribute__((address_space(1))) unsigned*)g,
        (__attribute__((address_space(3))) unsigned*)lds, 16, 0, 0);
  }
  __syncthreads();

  // ---- compute ----
  int c = l & 15, kg = l >> 4;
  int r = c;
  int xorr = (r & 7) << 4;
  const char* xsb = reinterpret_cast<const char*>(xs);
  const unsigned short* wp0 = WT + (size_t)c*512 + kg*8;

  f32x4 acc[4];
  #pragma unroll
  for (int j = 0; j < 4; j++) acc[j] = (f32x4){0.f,0.f,0.f,0.f};

  #pragma unroll
  for (int kt = 0; kt < 16; ++kt){
    int b0 = (kt*128 + kg*32) ^ xorr;
    int b1 = (kt*128 + kg*32 + 16) ^ xorr;
    float4 u0 = *reinterpret_cast<const float4*>(xsb + (size_t)r*2048 + b0);
    float4 u1 = *reinterpret_cast<const float4*>(xsb + (size_t)r*2048 + b1);
    union { unsigned u[4]; bf16x8 v; } cc;
    cc.u[0] = cvtpk(u0.x, u0.y);
    cc.u[1] = cvtpk(u0.z, u0.w);
    cc.u[2] = cvtpk(u1.x, u1.y);
    cc.u[3] = cvtpk(u1.z, u1.w);
    #pragma unroll
    for (int j = 0; j < 4; j++){
      bf16x8 b = *reinterpret_cast<const bf16x8*>(wp0 + j*8192 + kt*32);
      acc[j] = mfma_bf16(cc.v, b, acc[j]);
    }
  }

  // ---- epilogue: H store only ----
  #pragma unroll
  for (int j = 0; j < 4; j++){
    #pragma unroll
    for (int rr = 0; rr < 4; rr++){
      int grow = n0 + kg*4 + rr;
      if (grow < n) Hb[(size_t)grow*64 + j*16 + c] = f2bf(acc[j][rr]);
    }
  }
}

// ================= attention logits from bf16 H =================
__global__ void k_att(const unsigned short* __restrict__ Hb,
                      const float* __restrict__ as_, const float* __restrict__ ad_,
                      unsigned short* __restrict__ alsb, float* __restrict__ ald, int n){
  int i = blockIdx.x*256 + threadIdx.x;   // i = node*8 + head
  if (i >= n*8) return;
  int head = i & 7;
  uint4 pk = *reinterpret_cast<const uint4*>(Hb + (size_t)i*8);
  float h[8];
  h[0]=bf2f((unsigned short)pk.x); h[1]=bf2f((unsigned short)(pk.x>>16));
  h[2]=bf2f((unsigned short)pk.y); h[3]=bf2f((unsigned short)(pk.y>>16));
  h[4]=bf2f((unsigned short)pk.z); h[5]=bf2f((unsigned short)(pk.z>>16));
  h[6]=bf2f((unsigned short)pk.w); h[7]=bf2f((unsigned short)(pk.w>>16));
  float sv = 0.f, dv = 0.f;
  #pragma unroll
  for (int j = 0; j < 8; j++){
    sv = fmaf(h[j], as_[head*8+j], sv);
    dv = fmaf(h[j], ad_[head*8+j], dv);
  }
  alsb[i] = f2bf(sv); ald[i] = dv;
}

// ================= layer-2 GEMM (K=64, bf16 src), plain epilogue =================
__global__ __launch_bounds__(256) void k_gemm64(
    const unsigned short* __restrict__ Xh, const unsigned short* __restrict__ WT,
    unsigned short* __restrict__ Hb, int n)
{
  int t = threadIdx.x;
  int w = t >> 6, l = t & 63;
  int c = l & 15, kg = l >> 4;
  int n0 = blockIdx.x*64 + w*16;
  int row = min(n0 + c, n-1);
  f32x4 acc[4];
  #pragma unroll
  for (int j = 0; j < 4; j++) acc[j] = (f32x4){0.f,0.f,0.f,0.f};

  #pragma unroll
  for (int kt = 0; kt < 2; ++kt){
    int ko = kt*32 + kg*8;
    bf16x8 a = *reinterpret_cast<const bf16x8*>(Xh + (size_t)row*64 + ko);
    #pragma unroll
    for (int j = 0; j < 4; j++){
      bf16x8 b = *reinterpret_cast<const bf16x8*>(WT + (size_t)(j*16 + c)*64 + ko);
      acc[j] = mfma_bf16(a, b, acc[j]);
    }
  }
  #pragma unroll
  for (int j = 0; j < 4; j++){
    #pragma unroll
    for (int rr = 0; rr < 4; rr++){
      int grow = n0 + kg*4 + rr;
      if (grow < n) Hb[(size_t)grow*64 + j*16 + c] = f2bf(acc[j][rr]);
    }
  }
}

// ================= GAT aggregation: 8 lanes/node, 8-deep edge pipeline =============
struct EdgeBuf {
  float a0, a1, a2, a3;
  uint4 h0, h1, h2, h3;
};

__device__ __forceinline__ void loadEB(EdgeBuf& b, const int* __restrict__ col,
                                       int pos, int beg, int end,
                                       const unsigned short* __restrict__ ap,
                                       const unsigned short* __restrict__ Hp){
  int s0 = (pos   < end) ? col[pos]   : col[beg];
  int s1 = (pos+1 < end) ? col[pos+1] : s0;
  int s2 = (pos+2 < end) ? col[pos+2] : s0;
  int s3 = (pos+3 < end) ? col[pos+3] : s0;
  b.a0 = bf2f(ap[s0*8]); b.a1 = bf2f(ap[s1*8]);
  b.a2 = bf2f(ap[s2*8]); b.a3 = bf2f(ap[s3*8]);
  b.h0 = *reinterpret_cast<const uint4*>(Hp + (size_t)s0*64);
  b.h1 = *reinterpret_cast<const uint4*>(Hp + (size_t)s1*64);
  b.h2 = *reinterpret_cast<const uint4*>(Hp + (size_t)s2*64);
  b.h3 = *reinterpret_cast<const uint4*>(Hp + (size_t)s3*64);
}

__device__ __forceinline__ void acc8(float (&acc)[8], float xf, uint4 g){
  acc[0] = fmaf(xf, bf2f((unsigned short)g.x), acc[0]);
  acc[1] = fmaf(xf, bf2f((unsigned short)(g.x>>16)), acc[1]);
  acc[2] = fmaf(xf, bf2f((unsigned short)g.y), acc[2]);
  acc[3] = fmaf(xf, bf2f((unsigned short)(g.y>>16)), acc[3]);
  acc[4] = fmaf(xf, bf2f((unsigned short)g.z), acc[4]);
  acc[5] = fmaf(xf, bf2f((unsigned short)(g.z>>16)), acc[5]);
  acc[6] = fmaf(xf, bf2f((unsigned short)g.w), acc[6]);
  acc[7] = fmaf(xf, bf2f((unsigned short)(g.w>>16)), acc[7]);
}

__device__ __forceinline__ void computeEB(const EdgeBuf& b, int pos, int end, float adv,
                                          float& ssum, float (&acc)[8]){
  float e0 = b.a0 + adv; e0 = (e0>0.f)?e0:0.2f*e0;
  float e1 = b.a1 + adv; e1 = (e1>0.f)?e1:0.2f*e1;
  float e2 = b.a2 + adv; e2 = (e2>0.f)?e2:0.2f*e2;
  float e3 = b.a3 + adv; e3 = (e3>0.f)?e3:0.2f*e3;
  float x0 = __expf(e0);
  float x1 = (pos+1 < end) ? __expf(e1) : 0.f;
  float x2 = (pos+2 < end) ? __expf(e2) : 0.f;
  float x3 = (pos+3 < end) ? __expf(e3) : 0.f;
  ssum += (x0 + x1) + (x2 + x3);
  acc8(acc, x0, b.h0);
  acc8(acc, x1, b.h1);
  acc8(acc, x2, b.h2);
  acc8(acc, x3, b.h3);
}

template<bool DO_ELU>
__global__ __launch_bounds__(256) void k_agg(
    const int* __restrict__ rowptr, const int* __restrict__ col,
    const unsigned short* __restrict__ Hb, const unsigned short* __restrict__ alsb,
    const float* __restrict__ ald, const float* __restrict__ bias,
    unsigned short* __restrict__ outb, int n)
{
  int grp = threadIdx.x >> 3;           // 32 node-groups per block
  int ln  = threadIdx.x & 7;            // lane owns head ln (8 channels)
  int node = blockIdx.x*32 + grp;
  if (node >= n) return;
  float adv = ald[node*8 + ln];
  int beg = rowptr[node], end = rowptr[node+1];
  const unsigned short* Hp = Hb + ln*8;
  const unsigned short* ap = alsb + ln;

  float acc[8];
  #pragma unroll
  for (int q = 0; q < 8; q++) acc[q] = 0.f;
  float ssum = 0.f;

  EdgeBuf A, B;
  int p = beg;
  loadEB(A, col, p,   beg, end, ap, Hp);
  loadEB(B, col, p+4, beg, end, ap, Hp);
  while (true){
    computeEB(A, p, end, adv, ssum, acc);
    if (p + 8 < end) loadEB(A, col, p+8, beg, end, ap, Hp);
    p += 4;
    if (p >= end) break;
    computeEB(B, p, end, adv, ssum, acc);
    if (p + 8 < end) loadEB(B, col, p+8, beg, end, ap, Hp);
    p += 4;
    if (p >= end) break;
  }

  float inv = 1.f/ssum;
  ushort4 pk0, pk1;
  float o[8];
  #pragma unroll
  for (int q = 0; q < 8; q++){
    o[q] = acc[q]*inv + bias[ln*8 + q];
    if (DO_ELU) o[q] = (o[q] > 0.f) ? o[q] : (__expf(o[q]) - 1.f);
  }
  pk0.x = f2bf(o[0]); pk0.y = f2bf(o[1]); pk0.z = f2bf(o[2]); pk0.w = f2bf(o[3]);
  pk1.x = f2bf(o[4]); pk1.y = f2bf(o[5]); pk1.z = f2bf(o[6]); pk1.w = f2bf(o[7]);
  *reinterpret_cast<ushort4*>(outb + (size_t)node*64 + ln*8)     = pk0;
  *reinterpret_cast<ushort4*>(outb + (size_t)node*64 + ln*8 + 4) = pk1;
}

// ================= fused bidirectional 2-step LSTM (one dispatch) =================
__global__ __launch_bounds__(256) void k_lstm(
    const unsigned short* __restrict__ X1b, const unsigned short* __restrict__ X2b,
    const unsigned short* __restrict__ Wfx, const unsigned short* __restrict__ Wfh,
    const unsigned short* __restrict__ Wbx, const unsigned short* __restrict__ Wbh,
    const float* __restrict__ bihf, const float* __restrict__ bhhf,
    const float* __restrict__ bihb, const float* __restrict__ bhhb,
    const float* __restrict__ watt,
    float* __restrict__ pf0, float* __restrict__ pf1,
    float* __restrict__ pb0, float* __restrict__ pb1, int n)
{
  int dir = blockIdx.y;
  const unsigned short* X0 = dir ? X2b : X1b;   // step0 input
  const unsigned short* X1 = dir ? X1b : X2b;   // step1 input
  const unsigned short* Wx = dir ? Wbx : Wfx;
  const unsigned short* Wh = dir ? Wbh : Wfh;
  const float* bi = dir ? bihb : bihf;
  const float* bh = dir ? bhhb : bhhf;
  const float* wa = watt + dir*64;
  float* po0 = dir ? pb0 : pf0;
  float* po1 = dir ? pb1 : pf1;

  __shared__ unsigned short hls[32][72];   // padded: b128 reads -> 2-way (free)
  __shared__ float attp[2][4][32];

  int t = threadIdx.x;
  int w = t >> 6, l = t & 63;
  int c = l & 15, kg = l >> 4;
  int n0 = blockIdx.x*32;
  int r0 = min(n0 + c, n-1);
  int r1 = min(n0 + 16 + c, n-1);

  int hid = w*16 + c;
  float bs0 = bi[hid]       + bh[hid];
  float bs1 = bi[hid + 64]  + bh[hid + 64];
  float bs2 = bi[hid + 128] + bh[hid + 128];
  float bs3 = bi[hid + 192] + bh[hid + 192];
  float wav = wa[hid];

  // ---- step 0: gates = X0 @ Wx^T ----
  f32x4 acc[2][4];
  #pragma unroll
  for (int m = 0; m < 2; m++)
    #pragma unroll
    for (int g = 0; g < 4; g++) acc[m][g] = (f32x4){0.f,0.f,0.f,0.f};

  #pragma unroll
  for (int kt = 0; kt < 2; ++kt){
    int ko = kt*32 + kg*8;
    bf16x8 a0 = *reinterpret_cast<const bf16x8*>(X0 + (size_t)r0*64 + ko);
    bf16x8 a1 = *reinterpret_cast<const bf16x8*>(X0 + (size_t)r1*64 + ko);
    #pragma unroll
    for (int g = 0; g < 4; g++){
      bf16x8 b = *reinterpret_cast<const bf16x8*>(Wx + (size_t)(g*64 + hid)*64 + ko);
      acc[0][g] = mfma_bf16(a0, b, acc[0][g]);
      acc[1][g] = mfma_bf16(a1, b, acc[1][g]);
    }
  }
  float creg[2][4];
  #pragma unroll
  for (int m = 0; m < 2; m++){
    #pragma unroll
    for (int r = 0; r < 4; r++){
      int rl = m*16 + kg*4 + r;
      float gi = acc[m][0][r] + bs0;
      float gg = acc[m][2][r] + bs2;
      float go = acc[m][3][r] + bs3;
      float cc = fsigm(gi)*ftanh(gg);
      float hh = fsigm(go)*ftanh(cc);
      creg[m][r] = cc;
      hls[rl][hid] = f2bf(hh);
      float s = hh*wav;
      s += __shfl_xor(s, 1, 16);
      s += __shfl_xor(s, 2, 16);
      s += __shfl_xor(s, 4, 16);
      s += __shfl_xor(s, 8, 16);
      if (c == 0) attp[0][w][rl] = s;
    }
  }
  __syncthreads();

  // ---- step 1: gates = X1 @ Wx^T + h0 @ Wh^T ----
  #pragma unroll
  for (int m = 0; m < 2; m++)
    #pragma unroll
    for (int g = 0; g < 4; g++) acc[m][g] = (f32x4){0.f,0.f,0.f,0.f};

  #pragma unroll
  for (int kt = 0; kt < 4; ++kt){
    int ko = (kt & 1)*32 + kg*8;
    bf16x8 a0, a1;
    if (kt < 2){
      a0 = *reinterpret_cast<const bf16x8*>(X1 + (size_t)r0*64 + ko);
      a1 = *reinterpret_cast<const bf16x8*>(X1 + (size_t)r1*64 + ko);
    } else {
      a0 = *reinterpret_cast<const bf16x8*>(&hls[c][ko]);
      a1 = *reinterpret_cast<const bf16x8*>(&hls[16 + c][ko]);
    }
    const unsigned short* Wp = (kt < 2) ? Wx : Wh;
    #pragma unroll
    for (int g = 0; g < 4; g++){
      bf16x8 b = *reinterpret_cast<const bf16x8*>(Wp + (size_t)(g*64 + hid)*64 + ko);
      acc[0][g] = mfma_bf16(a0, b, acc[0][g]);
      acc[1][g] = mfma_bf16(a1, b, acc[1][g]);
    }
  }
  #pragma unroll
  for (int m = 0; m < 2; m++){
    #pragma unroll
    for (int r = 0; r < 4; r++){
      int rl = m*16 + kg*4 + r;
      float gi = acc[m][0][r] + bs0;
      float gf = acc[m][1][r] + bs1;
      float gg = acc[m][2][r] + bs2;
      float go = acc[m][3][r] + bs3;
      float cc = fsigm(gf)*creg[m][r] + fsigm(gi)*ftanh(gg);
      float hh = fsigm(go)*ftanh(cc);
      float s = hh*wav;
      s += __shfl_xor(s, 1, 16);
      s += __shfl_xor(s, 2, 16);
      s += __shfl_xor(s, 4, 16);
      s += __shfl_xor(s, 8, 16);
      if (c == 0) attp[1][w][rl] = s;
    }
  }
  __syncthreads();
  if (t < 32){
    int grow = n0 + t;
    if (grow < n) po0[grow] = attp[0][0][t] + attp[0][1][t] + attp[0][2][t] + attp[0][3][t];
  } else if (t < 64){
    int rr = t - 32;
    int grow = n0 + rr;
    if (grow < n) po1[grow] = attp[1][0][rr] + attp[1][1][rr] + attp[1][2][rr] + attp[1][3][rr];
  }
}

// ================= JK attention + output GEMM + log_softmax =================
__global__ __launch_bounds__(256) void k_final(
    const unsigned short* __restrict__ x1b, const unsigned short* __restrict__ x2b,
    const float* __restrict__ pf0, const float* __restrict__ pf1,
    const float* __restrict__ pb0, const float* __restrict__ pb1,
    const float* __restrict__ Wout, float* __restrict__ out, int n)
{
  __shared__ __align__(16) float ws[NCLS][68];
  __shared__ __align__(16) float fs[32][68];
  int t = threadIdx.x;
  for (int i = t; i < NCLS*64; i += 256)
    ws[i>>6][i&63] = Wout[i];

  int n0 = blockIdx.x*32;
  int nd = t >> 3, q8 = t & 7;
  int g = n0 + nd;
  int eb = q8*8;
  if (g < n){
    float att0 = pf0[g] + pb1[g];
    float att1 = pf1[g] + pb0[g];
    float a0 = 1.f/(1.f + __expf(att1 - att0));
    float a1 = 1.f - a0;
    uint4 p1 = *reinterpret_cast<const uint4*>(x1b + (size_t)g*64 + eb);
    uint4 p2 = *reinterpret_cast<const uint4*>(x2b + (size_t)g*64 + eb);
    const unsigned* u1 = (const unsigned*)&p1;
    const unsigned* u2 = (const unsigned*)&p2;
    #pragma unroll
    for (int q = 0; q < 4; q++){
      float v1l = bf2f((unsigned short)u1[q]), v1h = bf2f((unsigned short)(u1[q]>>16));
      float v2l = bf2f((unsigned short)u2[q]), v2h = bf2f((unsigned short)(u2[q]>>16));
      fs[nd][eb + q*2 + 0] = a0*v1l + a1*v2l;
      fs[nd][eb + q*2 + 1] = a0*v1h + a1*v2h;
    }
  } else {
    #pragma unroll
    for (int q = 0; q < 8; q++) fs[nd][eb+q] = 0.f;
  }
  __syncthreads();

  float lg[5] = {0.f,0.f,0.f,0.f,0.f};
  #pragma unroll
  for (int k4 = 0; k4 < 16; k4++){
    float4 f = *reinterpret_cast<const float4*>(&fs[nd][k4*4]);
    #pragma unroll
    for (int q = 0; q < 5; q++){
      int cc = q8 + 8*q;
      float4 wv = *reinterpret_cast<const float4*>(&ws[cc][k4*4]);
      lg[q] = fmaf(f.x, wv.x, lg[q]);
      lg[q] = fmaf(f.y, wv.y, lg[q]);
      lg[q] = fmaf(f.z, wv.z, lg[q]);
      lg[q] = fmaf(f.w, wv.w, lg[q]);
    }
  }
  float mx = lg[0];
  #pragma unroll
  for (int q = 1; q < 5; q++) mx = fmaxf(mx, lg[q]);
  #pragma unroll
  for (int mk = 1; mk < 8; mk <<= 1) mx = fmaxf(mx, __shfl_xor(mx, mk, 64));
  float se = 0.f;
  #pragma unroll
  for (int q = 0; q < 5; q++) se += __expf(lg[q] - mx);
  #pragma unroll
  for (int mk = 1; mk < 8; mk <<= 1) se += __shfl_xor(se, mk, 64);
  float lse = __logf(se);
  if (g < n){
    #pragma unroll
    for (int q = 0; q < 5; q++)
      out[(size_t)g*NCLS + q8 + 8*q] = lg[q] - mx - lse;
  }
}

// ================= host =================
extern "C" void kernel_launch(void* const* d_in, const int* in_sizes, int n_in,
                              void* d_out, int out_size, void* d_ws, size_t ws_size,
                              hipStream_t stream)
{
  const float* x    = (const float*)d_in[0];
  const int*   ei   = (const int*)d_in[1];
  const float* W1   = (const float*)d_in[2];
  const float* a1s  = (const float*)d_in[3];
  const float* a1d  = (const float*)d_in[4];
  const float* b1   = (const float*)d_in[5];
  const float* W2   = (const float*)d_in[6];
  const float* a2s  = (const float*)d_in[7];
  const float* a2d  = (const float*)d_in[8];
  const float* b2   = (const float*)d_in[9];
  const float* Wih_f= (const float*)d_in[10];
  const float* Whh_f= (const float*)d_in[11];
  const float* bih_f= (const float*)d_in[12];
  const float* bhh_f= (const float*)d_in[13];
  const float* Wih_b= (const float*)d_in[14];
  const float* Whh_b= (const float*)d_in[15];
  const float* bih_b= (const float*)d_in[16];
  const float* bhh_b= (const float*)d_in[17];
  const float* watt = (const float*)d_in[18];
  const float* Wout = (const float*)d_in[20];
  float* out = (float*)d_out;

  int n = in_sizes[0] / F_IN;   // 100000
  int e = in_sizes[1] / 2;      // 1600000
  int nb = (n + BNODES - 1) >> BSH;       // buckets of 128 nodes (782)
  int B  = (e + n + CH - 1) / CH;         // partition blocks (~104)

  char* p = (char*)d_ws;
  auto alloc = [&](size_t b)->char*{ char* r = p; p += (b + 255) & ~(size_t)255; return r; };
  int* rowptr = (int*)alloc((size_t)(n+1)*4);
  int* colidx = (int*)alloc((size_t)(e+n)*4);
  unsigned* bedges = (unsigned*)alloc((size_t)(e+n)*4);
  int* bhist  = (int*)alloc((size_t)B*nb*4);
  int* bcnt   = (int*)alloc((size_t)(nb+1)*4);
  int* bbase  = (int*)alloc((size_t)(nb+1)*4);
  unsigned short* hbuf = (unsigned short*)alloc((size_t)n*64*2);   // bf16 H
  unsigned short* alsb = (unsigned short*)alloc((size_t)n*8*2);    // bf16 als
  float* ald  = (float*)alloc((size_t)n*8*4);
  unsigned short* x1b = (unsigned short*)alloc((size_t)n*64*2);
  unsigned short* x2b = (unsigned short*)alloc((size_t)n*64*2);
  float* pf0 = (float*)alloc((size_t)n*4);
  float* pf1 = (float*)alloc((size_t)n*4);
  float* pb0 = (float*)alloc((size_t)n*4);
  float* pb1 = (float*)alloc((size_t)n*4);
  unsigned short* W1T = (unsigned short*)alloc((size_t)64*512*2);
  unsigned short* W2T = (unsigned short*)alloc((size_t)64*64*2);
  unsigned short* Wfx = (unsigned short*)alloc((size_t)256*64*2);
  unsigned short* Wfh = (unsigned short*)alloc((size_t)256*64*2);
  unsigned short* Wbx = (unsigned short*)alloc((size_t)256*64*2);
  unsigned short* Wbh = (unsigned short*)alloc((size_t)256*64*2);

  // ---- CSR build (block-aggregated partition, no global atomics) ----
  k_pcount<<<B, 256, 0, stream>>>(ei, e, n, nb, bhist);
  k_pscan1<<<(nb+255)/256, 256, 0, stream>>>(bhist, nb, B, bcnt);
  k_pscan2<<<1, 256, 0, stream>>>(bcnt, nb, e+n, bbase, rowptr, n);
  k_pscatter<<<B, 256, 0, stream>>>(ei, e, n, nb, bhist, bbase, bedges);
  k_bbuild<<<nb, 256, 0, stream>>>(bedges, bbase, rowptr, colidx, n);

  // ---- weight conversion (single dispatch) ----
  k_prep<<<400, 256, 0, stream>>>(W1, W2, Wih_f, Whh_f, Wih_b, Whh_b,
                                  W1T, W2T, Wfx, Wfh, Wbx, Wbh);

  // ---- GAT layers ----
  k_gemm512<<<(n + 15)/16, 64, 0, stream>>>(x, W1T, hbuf, n);
  k_att<<<(n*8+255)/256, 256, 0, stream>>>(hbuf, a1s, a1d, alsb, ald, n);
  k_agg<true ><<<(n+31)/32, 256, 0, stream>>>(rowptr, colidx, hbuf, alsb, ald, b1, x1b, n);
  k_gemm64<<<(n + 63)/64, 256, 0, stream>>>(x1b, W2T, hbuf, n);
  k_att<<<(n*8+255)/256, 256, 0, stream>>>(hbuf, a2s, a2d, alsb, ald, n);
  k_agg<false><<<(n+31)/32, 256, 0, stream>>>(rowptr, colidx, hbuf, alsb, ald, b2, x2b, n);

  // ---- JK LSTM: both directions, both steps, one dispatch ----
  dim3 lgrid((n + 31)/32, 2);
  k_lstm<<<lgrid, 256, 0, stream>>>(x1b, x2b, Wfx, Wfh, Wbx, Wbh,
                                    bih_f, bhh_f, bih_b, bhh_b,
                                    watt, pf0, pf1, pb0, pb1, n);

  // ---- output layer ----
  k_final<<<(n+3)/4, 256, 0, stream>>>(x1b, x2b, pf0, pf1, pb0, pb1, Wout, out, n);
}